// Round 6
// baseline (589.574 us; speedup 1.0000x reference)
//
#include <hip/hip_runtime.h>
#include <hip/hip_fp16.h>
#include <math.h>

// ---------------------------------------------------------------------------
// SNEA via CSR-pull with packed bin records.
//   CSR build: binned counting sort (bin = dst>>9); esrc stores PACKED record
//              (src<<9 | dstLocal) so later kernels recover dst without a map.
//   wgt kernels (per bin, edge-parallel): w = exp(si[dst]+sj[src]) written per
//              CSR slot; den accumulated in LDS per bin; rden[node] stored.
//              (no segment-max: scores ~N(0,1), unstabilized exp is f32-safe
//               and mathematically identical). Layer 2 packs both families'
//              weights as half2 per edge.
//   agg kernels: one wave per dst node, pure broadcast-gather: per 64-edge
//              chunk one coalesced wgt+rec load, then 8 edges in flight via
//              8 groups x 8 lanes x uint4 (128B fp16 row), f32 accumulate,
//              3-round shfl reduce, scale by rden, vectorized store.
// ---------------------------------------------------------------------------

#define BIN_SHIFT 9
#define BIN_SPAN  512
#define NBIN_MAX  256          // n <= 131072; src fits 23 bits

// ----------------------------- CSR build ----------------------------------

__global__ __launch_bounds__(256) void bin_hist_kernel(const int* __restrict__ dst, int E,
                                                       int* __restrict__ binCnt, int nbin) {
    __shared__ int lc[NBIN_MAX];
    if (threadIdx.x < NBIN_MAX) lc[threadIdx.x] = 0;
    __syncthreads();
    int i = blockIdx.x * blockDim.x + threadIdx.x;
    int stride = gridDim.x * blockDim.x;
    for (; i < E; i += stride) atomicAdd(&lc[dst[i] >> BIN_SHIFT], 1);
    __syncthreads();
    if (threadIdx.x < nbin && lc[threadIdx.x]) atomicAdd(&binCnt[threadIdx.x], lc[threadIdx.x]);
}

__global__ __launch_bounds__(256) void scan_bins_kernel(const int* __restrict__ binCnt, int nbin,
                                                        int* __restrict__ binBase,
                                                        int* __restrict__ gCursor,
                                                        int* __restrict__ rowptr, int n, int E) {
    __shared__ int sd[256];
    int tid = threadIdx.x;
    int v = (tid < nbin) ? binCnt[tid] : 0;
    sd[tid] = v; __syncthreads();
    for (int off = 1; off < 256; off <<= 1) {
        int t = (tid >= off) ? sd[tid - off] : 0;
        __syncthreads();
        sd[tid] += t;
        __syncthreads();
    }
    if (tid < nbin) { binBase[tid] = sd[tid] - v; gCursor[tid] = 0; }
    if (tid == nbin - 1) binBase[nbin] = sd[tid];
    if (tid == 0) rowptr[n] = E;
}

// block-aggregated binning scatter; packed record = (src << BIN_SHIFT) | dstLocal.
__global__ __launch_bounds__(256) void bin_scatter_kernel(
        const int* __restrict__ src, const int* __restrict__ dst, int E,
        const int* __restrict__ binBase, int* __restrict__ gCursor,
        int* __restrict__ binned, int nbin) {
    __shared__ int lc[NBIN_MAX];
    __shared__ int lbase[NBIN_MAX];
    if (threadIdx.x < NBIN_MAX) lc[threadIdx.x] = 0;
    __syncthreads();
    int base0 = blockIdx.x * 4096 + threadIdx.x * 16;
    int rank[16], bn[16];
    #pragma unroll
    for (int k = 0; k < 16; ++k) {
        int i = base0 + k;
        if (i < E) {
            int b = dst[i] >> BIN_SHIFT;
            bn[k] = b;
            rank[k] = atomicAdd(&lc[b], 1);
        }
    }
    __syncthreads();
    if (threadIdx.x < nbin && lc[threadIdx.x])
        lbase[threadIdx.x] = atomicAdd(&gCursor[threadIdx.x], lc[threadIdx.x]);
    __syncthreads();
    #pragma unroll
    for (int k = 0; k < 16; ++k) {
        int i = base0 + k;
        if (i < E) {
            int b = bn[k];
            int pos = binBase[b] + lbase[b] + rank[k];
            binned[pos] = (src[i] << BIN_SHIFT) | (dst[i] & (BIN_SPAN - 1));
        }
    }
}

// one block per bin: per-dst hist -> scan -> rowptr -> scatter PACKED rec.
__global__ __launch_bounds__(256) void bin_finalize_kernel(
        const int* __restrict__ binned, const int* __restrict__ binBase,
        int* __restrict__ rowptr, int* __restrict__ esrc, int n) {
    __shared__ int hist[BIN_SPAN];
    __shared__ int curs[BIN_SPAN];
    __shared__ int psum[256];
    int b = blockIdx.x, tid = threadIdx.x;
    int lo = binBase[b], hi = binBase[b + 1];
    int nodeBase = b << BIN_SHIFT;
    hist[tid] = 0; hist[tid + 256] = 0;
    __syncthreads();
    for (int i = lo + tid; i < hi; i += 256)
        atomicAdd(&hist[binned[i] & (BIN_SPAN - 1)], 1);
    __syncthreads();
    int a0 = hist[2 * tid], a1 = hist[2 * tid + 1];
    int ps = a0 + a1;
    psum[tid] = ps; __syncthreads();
    for (int off = 1; off < 256; off <<= 1) {
        int t = (tid >= off) ? psum[tid - off] : 0;
        __syncthreads();
        psum[tid] += t;
        __syncthreads();
    }
    int excl = psum[tid] - ps;
    curs[2 * tid] = excl;
    curs[2 * tid + 1] = excl + a0;
    {
        int idx0 = nodeBase + 2 * tid;
        if (idx0 <= n)     rowptr[idx0]     = lo + excl;
        if (idx0 + 1 <= n) rowptr[idx0 + 1] = lo + excl + a0;
    }
    __syncthreads();
    for (int i = lo + tid; i < hi; i += 256) {
        int rec = binned[i];
        int slot = lo + atomicAdd(&curs[rec & (BIN_SPAN - 1)], 1);
        esrc[slot] = rec;      // keep packed
    }
}

// --------------------------- per-node scalars ------------------------------

__global__ __launch_bounds__(256) void scalars1_kernel(
        const float* __restrict__ x,
        const float* __restrict__ a1b, const float* __restrict__ a1u,
        float* __restrict__ S, __half* __restrict__ xh, int n) {
    __shared__ float sA[256];
    for (int k = threadIdx.x; k < 256; k += blockDim.x)
        sA[k] = (k < 128) ? a1b[k] : a1u[k - 128];
    __syncthreads();
    int grp = threadIdx.x >> 4, l = threadIdx.x & 15;
    for (int row = blockIdx.x * 16 + grp; row < n; row += gridDim.x * 16) {
        const float4 v = *(const float4*)(x + (size_t)row * 64 + l * 4);
        __half2 h0 = __floats2half2_rn(v.x, v.y);
        __half2 h1 = __floats2half2_rn(v.z, v.w);
        uint2 pk = make_uint2(*(unsigned*)&h0, *(unsigned*)&h1);
        *(uint2*)(xh + (size_t)row * 64 + l * 4) = pk;
        const float4 A0 = *(const float4*)(sA + l * 4);
        const float4 A1 = *(const float4*)(sA + 64 + l * 4);
        const float4 A2 = *(const float4*)(sA + 128 + l * 4);
        const float4 A3 = *(const float4*)(sA + 192 + l * 4);
        float p0 = fmaf(v.x, A0.x, fmaf(v.y, A0.y, fmaf(v.z, A0.z, v.w * A0.w)));
        float p1 = fmaf(v.x, A1.x, fmaf(v.y, A1.y, fmaf(v.z, A1.z, v.w * A1.w)));
        float p2 = fmaf(v.x, A2.x, fmaf(v.y, A2.y, fmaf(v.z, A2.z, v.w * A2.w)));
        float p3 = fmaf(v.x, A3.x, fmaf(v.y, A3.y, fmaf(v.z, A3.z, v.w * A3.w)));
        #pragma unroll
        for (int off = 1; off < 16; off <<= 1) {
            p0 += __shfl_xor(p0, off);
            p1 += __shfl_xor(p1, off);
            p2 += __shfl_xor(p2, off);
            p3 += __shfl_xor(p3, off);
        }
        if (l == 0) {
            S[row] = p0;
            S[(size_t)n + row] = p1;
            S[2 * (size_t)n + row] = p2;
            S[3 * (size_t)n + row] = p3;
        }
    }
}

__global__ __launch_bounds__(256) void scalars2_kernel(
        const float* __restrict__ z,
        const float* __restrict__ a2b, const float* __restrict__ a2u,
        float* __restrict__ S, __half* __restrict__ zh, int n) {
    __shared__ float sA[128];
    for (int k = threadIdx.x; k < 128; k += blockDim.x)
        sA[k] = (k < 64) ? a2b[k] : a2u[k - 64];
    __syncthreads();
    int grp = threadIdx.x >> 4, l = threadIdx.x & 15;
    int aoff = (l & 7) * 4;
    for (int row = blockIdx.x * 16 + grp; row < n; row += gridDim.x * 16) {
        const float4 v = *(const float4*)(z + (size_t)row * 64 + l * 4);
        __half2 h0 = __floats2half2_rn(v.x, v.y);
        __half2 h1 = __floats2half2_rn(v.z, v.w);
        uint2 pk = make_uint2(*(unsigned*)&h0, *(unsigned*)&h1);
        *(uint2*)(zh + (size_t)row * 64 + l * 4) = pk;
        const float4 A0 = *(const float4*)(sA + aoff);
        const float4 A1 = *(const float4*)(sA + 32 + aoff);
        const float4 A2 = *(const float4*)(sA + 64 + aoff);
        const float4 A3 = *(const float4*)(sA + 96 + aoff);
        float q0 = fmaf(v.x, A0.x, fmaf(v.y, A0.y, fmaf(v.z, A0.z, v.w * A0.w)));
        float q1 = fmaf(v.x, A1.x, fmaf(v.y, A1.y, fmaf(v.z, A1.z, v.w * A1.w)));
        float q2 = fmaf(v.x, A2.x, fmaf(v.y, A2.y, fmaf(v.z, A2.z, v.w * A2.w)));
        float q3 = fmaf(v.x, A3.x, fmaf(v.y, A3.y, fmaf(v.z, A3.z, v.w * A3.w)));
        #pragma unroll
        for (int off = 1; off < 8; off <<= 1) {
            q0 += __shfl_xor(q0, off);
            q1 += __shfl_xor(q1, off);
            q2 += __shfl_xor(q2, off);
            q3 += __shfl_xor(q3, off);
        }
        if (l == 0) {          // zb dots -> S0,S1,S6,S7
            S[row] = q0;
            S[(size_t)n + row] = q1;
            S[6 * (size_t)n + row] = q2;
            S[7 * (size_t)n + row] = q3;
        } else if (l == 8) {   // zu dots -> S2,S3,S4,S5
            S[2 * (size_t)n + row] = q0;
            S[3 * (size_t)n + row] = q1;
            S[4 * (size_t)n + row] = q2;
            S[5 * (size_t)n + row] = q3;
        }
    }
}

// ----------------------- per-edge weights + den ----------------------------

// Layer 1: one block per bin, handles pos and neg slots of that bin.
__global__ __launch_bounds__(1024) void wgt1_kernel(
        const int* __restrict__ esrcP, const int* __restrict__ binBaseP,
        const int* __restrict__ esrcN, const int* __restrict__ binBaseN,
        const float* __restrict__ S,
        float* __restrict__ wgtP, float* __restrict__ wgtN,
        float* __restrict__ rdenP, float* __restrict__ rdenN, int n) {
    __shared__ float dP[BIN_SPAN], dN[BIN_SPAN];
    int b = blockIdx.x, tid = threadIdx.x;
    if (tid < BIN_SPAN) { dP[tid] = 0.f; dN[tid] = 0.f; }
    __syncthreads();
    int nodeBase = b << BIN_SHIFT;
    const float* siP = S;                     const float* sjP = S + (size_t)n;
    const float* siN = S + 2 * (size_t)n;     const float* sjN = S + 3 * (size_t)n;
    for (int i = binBaseP[b] + tid, hi = binBaseP[b + 1]; i < hi; i += 1024) {
        int rec = esrcP[i];
        int src = (int)((unsigned)rec >> BIN_SHIFT);
        int dl  = rec & (BIN_SPAN - 1);
        float w = __expf(siP[nodeBase + dl] + sjP[src]);
        wgtP[i] = w;
        atomicAdd(&dP[dl], w);
    }
    for (int i = binBaseN[b] + tid, hi = binBaseN[b + 1]; i < hi; i += 1024) {
        int rec = esrcN[i];
        int src = (int)((unsigned)rec >> BIN_SHIFT);
        int dl  = rec & (BIN_SPAN - 1);
        float w = __expf(siN[nodeBase + dl] + sjN[src]);
        wgtN[i] = w;
        atomicAdd(&dN[dl], w);
    }
    __syncthreads();
    if (tid < BIN_SPAN) {
        int node = nodeBase + tid;
        if (node < n) {
            rdenP[node] = 1.0f / fmaxf(dP[tid], 1e-16f);
            rdenN[node] = 1.0f / fmaxf(dN[tid], 1e-16f);
        }
    }
}

// Layer 2: both families per edge set; weight pair packed as half2 per slot.
// pos: L=bp(S0,S1) H=up(S4,S5).  neg: L=un(S6,S7) H=bn(S2,S3).
__global__ __launch_bounds__(1024) void wgt2_kernel(
        const int* __restrict__ esrcP, const int* __restrict__ binBaseP,
        const int* __restrict__ esrcN, const int* __restrict__ binBaseN,
        const float* __restrict__ S,
        unsigned* __restrict__ wgtP, unsigned* __restrict__ wgtN,
        float* __restrict__ rdenPL, float* __restrict__ rdenPH,
        float* __restrict__ rdenNL, float* __restrict__ rdenNH, int n) {
    __shared__ float dPL[BIN_SPAN], dPH[BIN_SPAN], dNL[BIN_SPAN], dNH[BIN_SPAN];
    int b = blockIdx.x, tid = threadIdx.x;
    if (tid < BIN_SPAN) { dPL[tid] = 0.f; dPH[tid] = 0.f; dNL[tid] = 0.f; dNH[tid] = 0.f; }
    __syncthreads();
    int nodeBase = b << BIN_SHIFT;
    const float* S0 = S;                   const float* S1 = S + (size_t)n;
    const float* S2 = S + 2 * (size_t)n;   const float* S3 = S + 3 * (size_t)n;
    const float* S4 = S + 4 * (size_t)n;   const float* S5 = S + 5 * (size_t)n;
    const float* S6 = S + 6 * (size_t)n;   const float* S7 = S + 7 * (size_t)n;
    for (int i = binBaseP[b] + tid, hi = binBaseP[b + 1]; i < hi; i += 1024) {
        int rec = esrcP[i];
        int src = (int)((unsigned)rec >> BIN_SHIFT);
        int dl  = rec & (BIN_SPAN - 1);
        float wL = __expf(S0[nodeBase + dl] + S1[src]);   // bp
        float wH = __expf(S4[nodeBase + dl] + S5[src]);   // up
        __half2 h = __floats2half2_rn(wL, wH);
        wgtP[i] = *(unsigned*)&h;
        atomicAdd(&dPL[dl], wL);
        atomicAdd(&dPH[dl], wH);
    }
    for (int i = binBaseN[b] + tid, hi = binBaseN[b + 1]; i < hi; i += 1024) {
        int rec = esrcN[i];
        int src = (int)((unsigned)rec >> BIN_SHIFT);
        int dl  = rec & (BIN_SPAN - 1);
        float wL = __expf(S6[nodeBase + dl] + S7[src]);   // un
        float wH = __expf(S2[nodeBase + dl] + S3[src]);   // bn
        __half2 h = __floats2half2_rn(wL, wH);
        wgtN[i] = *(unsigned*)&h;
        atomicAdd(&dNL[dl], wL);
        atomicAdd(&dNH[dl], wH);
    }
    __syncthreads();
    if (tid < BIN_SPAN) {
        int node = nodeBase + tid;
        if (node < n) {
            rdenPL[node] = 1.0f / fmaxf(dPL[tid], 1e-16f);
            rdenPH[node] = 1.0f / fmaxf(dPH[tid], 1e-16f);
            rdenNL[node] = 1.0f / fmaxf(dNL[tid], 1e-16f);
            rdenNH[node] = 1.0f / fmaxf(dNH[tid], 1e-16f);
        }
    }
}

// --------------------------- aggregations ----------------------------------

// Layer 1, D=64, pos+neg fused. 8 groups x 8 lanes, uint4 (8 halves) each.
__global__ __launch_bounds__(256) void agg64_kernel(
        const int* __restrict__ rpA, const int* __restrict__ esA,
        const float* __restrict__ wA, const float* __restrict__ rdA, float* __restrict__ outA,
        const int* __restrict__ rpB, const int* __restrict__ esB,
        const float* __restrict__ wB, const float* __restrict__ rdB, float* __restrict__ outB,
        const __half* __restrict__ xh, int n) {
    int w = threadIdx.x >> 6, lane = threadIdx.x & 63;
    int idx = blockIdx.x * 4 + w;
    if (idx >= 2 * n) return;
    bool second = idx >= n;
    int node = second ? idx - n : idx;
    const int*   rp = second ? rpB : rpA;
    const int*   es = second ? esB : esA;
    const float* wg = second ? wB : wA;
    const float* rd = second ? rdB : rdA;
    float*       op = second ? outB : outA;

    int start = rp[node], len = rp[node + 1] - start;
    int g3 = lane >> 3, q8 = lane & 7;
    float a0=0,a1=0,a2=0,a3=0,a4=0,a5=0,a6=0,a7=0;

    for (int cb = 0; cb < len; cb += 64) {
        int t = cb + lane;
        float wv = 0.f; int sr = 0;
        if (t < len) { wv = wg[start + t]; sr = es[start + t]; }
        int cl = len - cb; if (cl > 64) cl = 64;
        #pragma unroll 2
        for (int u = 0; u < cl; u += 8) {
            int e = u + g3;
            float wt = __shfl(wv, e);
            int   sp = __shfl(sr, e);
            if (e < cl) {
                size_t st = (size_t)((unsigned)sp >> BIN_SHIFT);
                const uint4 pk = *(const uint4*)(xh + st * 64 + q8 * 8);
                float2 f0 = __half22float2(*(const __half2*)&pk.x);
                float2 f1 = __half22float2(*(const __half2*)&pk.y);
                float2 f2 = __half22float2(*(const __half2*)&pk.z);
                float2 f3 = __half22float2(*(const __half2*)&pk.w);
                a0 = fmaf(wt, f0.x, a0); a1 = fmaf(wt, f0.y, a1);
                a2 = fmaf(wt, f1.x, a2); a3 = fmaf(wt, f1.y, a3);
                a4 = fmaf(wt, f2.x, a4); a5 = fmaf(wt, f2.y, a5);
                a6 = fmaf(wt, f3.x, a6); a7 = fmaf(wt, f3.y, a7);
            }
        }
    }
    #pragma unroll
    for (int off = 8; off <= 32; off <<= 1) {
        a0 += __shfl_xor(a0, off); a1 += __shfl_xor(a1, off);
        a2 += __shfl_xor(a2, off); a3 += __shfl_xor(a3, off);
        a4 += __shfl_xor(a4, off); a5 += __shfl_xor(a5, off);
        a6 += __shfl_xor(a6, off); a7 += __shfl_xor(a7, off);
    }
    if (g3 == 0) {
        float r = rd[node];
        float4 o0 = { a0 * r, a1 * r, a2 * r, a3 * r };
        float4 o1 = { a4 * r, a5 * r, a6 * r, a7 * r };
        float* dst = op + (size_t)node * 64 + q8 * 8;
        *(float4*)dst = o0;
        *(float4*)(dst + 4) = o1;
    }
}

// Layer 2: two aggregations per edge set; weight pair (L,H) packed half2/edge.
// Lanes q8<4 accumulate L family (zb cols 0-31), q8>=4 H family (zu 32-63).
__global__ __launch_bounds__(256) void agg32pair_kernel(
        const int* __restrict__ rpA, const int* __restrict__ esA,
        const unsigned* __restrict__ wA,
        const float* __restrict__ rdLA, const float* __restrict__ rdHA,
        float* __restrict__ outLA, float* __restrict__ outHA,
        const int* __restrict__ rpB, const int* __restrict__ esB,
        const unsigned* __restrict__ wB,
        const float* __restrict__ rdLB, const float* __restrict__ rdHB,
        float* __restrict__ outLB, float* __restrict__ outHB,
        const __half* __restrict__ zh, int n) {
    int w = threadIdx.x >> 6, lane = threadIdx.x & 63;
    int idx = blockIdx.x * 4 + w;
    if (idx >= 2 * n) return;
    bool second = idx >= n;
    int node = second ? idx - n : idx;
    const int*      rp  = second ? rpB  : rpA;
    const int*      es  = second ? esB  : esA;
    const unsigned* wg  = second ? wB   : wA;
    const float*    rdL = second ? rdLB : rdLA;
    const float*    rdH = second ? rdHB : rdHA;
    float* outL = second ? outLB : outLA;
    float* outH = second ? outHB : outHA;

    int start = rp[node], len = rp[node + 1] - start;
    int g3 = lane >> 3, q8 = lane & 7;
    bool lowf = q8 < 4;
    float a0=0,a1=0,a2=0,a3=0,a4=0,a5=0,a6=0,a7=0;

    for (int cb = 0; cb < len; cb += 64) {
        int t = cb + lane;
        unsigned wv = 0; int sr = 0;
        if (t < len) { wv = wg[start + t]; sr = es[start + t]; }
        int cl = len - cb; if (cl > 64) cl = 64;
        #pragma unroll 2
        for (int u = 0; u < cl; u += 8) {
            int e = u + g3;
            unsigned wp = (unsigned)__shfl((int)wv, e);
            int      sp = __shfl(sr, e);
            if (e < cl) {
                float2 wf = __half22float2(*(const __half2*)&wp);
                float wt = lowf ? wf.x : wf.y;
                size_t st = (size_t)((unsigned)sp >> BIN_SHIFT);
                const uint4 pk = *(const uint4*)(zh + st * 64 + q8 * 8);
                float2 f0 = __half22float2(*(const __half2*)&pk.x);
                float2 f1 = __half22float2(*(const __half2*)&pk.y);
                float2 f2 = __half22float2(*(const __half2*)&pk.z);
                float2 f3 = __half22float2(*(const __half2*)&pk.w);
                a0 = fmaf(wt, f0.x, a0); a1 = fmaf(wt, f0.y, a1);
                a2 = fmaf(wt, f1.x, a2); a3 = fmaf(wt, f1.y, a3);
                a4 = fmaf(wt, f2.x, a4); a5 = fmaf(wt, f2.y, a5);
                a6 = fmaf(wt, f3.x, a6); a7 = fmaf(wt, f3.y, a7);
            }
        }
    }
    #pragma unroll
    for (int off = 8; off <= 32; off <<= 1) {
        a0 += __shfl_xor(a0, off); a1 += __shfl_xor(a1, off);
        a2 += __shfl_xor(a2, off); a3 += __shfl_xor(a3, off);
        a4 += __shfl_xor(a4, off); a5 += __shfl_xor(a5, off);
        a6 += __shfl_xor(a6, off); a7 += __shfl_xor(a7, off);
    }
    if (g3 == 0) {
        float r = lowf ? rdL[node] : rdH[node];
        float4 o0 = { a0 * r, a1 * r, a2 * r, a3 * r };
        float4 o1 = { a4 * r, a5 * r, a6 * r, a7 * r };
        float* dst = lowf ? (outL + (size_t)node * 32 + q8 * 8)
                          : (outH + (size_t)node * 32 + (q8 - 4) * 8);
        *(float4*)dst = o0;
        *(float4*)(dst + 4) = o1;
    }
}

// ------------------------------- MLPs --------------------------------------

__global__ __launch_bounds__(256) void mlp1_kernel(
        const float* __restrict__ aggP, const float* __restrict__ aggN,
        const float* __restrict__ x,
        const float* __restrict__ W1b, const float* __restrict__ b1b,
        const float* __restrict__ W1u, const float* __restrict__ b1u,
        float* __restrict__ zout, int n) {
    __shared__ float sW[2][128 * 32];
    __shared__ float sB[2][32];
    __shared__ float sIn[4][192];
    for (int k = threadIdx.x; k < 128 * 32; k += 256) { sW[0][k] = W1b[k]; sW[1][k] = W1u[k]; }
    if (threadIdx.x < 32) { sB[0][threadIdx.x] = b1b[threadIdx.x]; sB[1][threadIdx.x] = b1u[threadIdx.x]; }
    __syncthreads();
    int g = threadIdx.x >> 6, u = threadIdx.x & 63;
    int half = u >> 5, col = u & 31;
    for (int base = blockIdx.x * 4; base < n; base += gridDim.x * 4) {
        int node = base + g;
        if (node < n) {
            for (int k = u; k < 192; k += 64) {
                float v;
                if (k < 64)       v = aggP[(size_t)node * 64 + k];
                else if (k < 128) v = aggN[(size_t)node * 64 + (k - 64)];
                else              v = x[(size_t)node * 64 + (k - 128)];
                sIn[g][k] = v;
            }
        }
        __syncthreads();
        if (node < n) {
            float acc = sB[half][col];
            const float* wp = sW[half];
            const float* in = sIn[g];
            int o = half * 64;
            #pragma unroll
            for (int k = 0; k < 64; ++k)   acc = fmaf(in[o + k],  wp[k * 32 + col], acc);
            #pragma unroll
            for (int k = 64; k < 128; ++k) acc = fmaf(in[64 + k], wp[k * 32 + col], acc);
            zout[(size_t)node * 64 + half * 32 + col] = tanhf(acc);
        }
        __syncthreads();
    }
}

__global__ __launch_bounds__(256) void mlp2_kernel(
        const float* __restrict__ aggBP, const float* __restrict__ aggBN,
        const float* __restrict__ aggUP, const float* __restrict__ aggUN,
        const float* __restrict__ W2b, const float* __restrict__ b2b,
        const float* __restrict__ W2u, const float* __restrict__ b2u,
        float* __restrict__ out, int n) {
    __shared__ float sW[2][96 * 32];
    __shared__ float sB[2][32];
    __shared__ float sIn[4][192];
    for (int k = threadIdx.x; k < 96 * 32; k += 256) { sW[0][k] = W2b[k]; sW[1][k] = W2u[k]; }
    if (threadIdx.x < 32) { sB[0][threadIdx.x] = b2b[threadIdx.x]; sB[1][threadIdx.x] = b2u[threadIdx.x]; }
    __syncthreads();
    int g = threadIdx.x >> 6, u = threadIdx.x & 63;
    int half = u >> 5, col = u & 31;
    for (int base = blockIdx.x * 4; base < n; base += gridDim.x * 4) {
        int node = base + g;
        if (node < n) {
            for (int k = u; k < 192; k += 64) {
                float v;
                if (k < 32)       v = aggBP[(size_t)node * 32 + k];
                else if (k < 64)  v = aggBN[(size_t)node * 32 + (k - 32)];
                else if (k < 96)  v = aggUP[(size_t)node * 32 + (k - 64)];
                else if (k < 128) v = aggUN[(size_t)node * 32 + (k - 96)];
                else              v = out[(size_t)node * 64 + (k - 128)];
                sIn[g][k] = v;
            }
        }
        __syncthreads();
        if (node < n) {
            float acc = sB[half][col];
            const float* wp = sW[half];
            const float* in = sIn[g];
            #pragma unroll
            for (int k = 0; k < 64; ++k)  acc = fmaf(in[half * 64 + k],      wp[k * 32 + col], acc);
            #pragma unroll
            for (int k = 64; k < 96; ++k) acc = fmaf(in[64 + k + half * 32], wp[k * 32 + col], acc);
            out[(size_t)node * 64 + half * 32 + col] = tanhf(acc);
        }
        __syncthreads();
    }
}

// ------------------------------ launcher -----------------------------------

extern "C" void kernel_launch(void* const* d_in, const int* in_sizes, int n_in,
                              void* d_out, int out_size, void* d_ws, size_t ws_size,
                              hipStream_t stream) {
    const float* x   = (const float*)d_in[0];
    const int*   pos = (const int*)d_in[1];
    const int*   neg = (const int*)d_in[2];
    const float* a1b = (const float*)d_in[3];
    const float* a1u = (const float*)d_in[4];
    const float* W1b = (const float*)d_in[5];
    const float* b1b = (const float*)d_in[6];
    const float* W1u = (const float*)d_in[7];
    const float* b1u = (const float*)d_in[8];
    const float* a2b = (const float*)d_in[9];
    const float* a2u = (const float*)d_in[10];
    const float* W2b = (const float*)d_in[11];
    const float* b2b = (const float*)d_in[12];
    const float* W2u = (const float*)d_in[13];
    const float* b2u = (const float*)d_in[14];
    float* out = (float*)d_out;

    const int n  = in_sizes[0] / 64;
    const int Ep = in_sizes[1] / 2;
    const int En = in_sizes[2] / 2;
    const int* ps = pos;  const int* pd = pos + Ep;
    const int* ns = neg;  const int* nd = neg + En;
    const int nbin = (n + BIN_SPAN - 1) >> BIN_SHIFT;   // 196 for n=100000

    // ws layout (4-byte words), 16B-aligned where vector loads require it:
    unsigned* W = (unsigned*)d_ws;
    size_t o = 0;
    float* S        = (float*)(W + o); o += 8 * (size_t)n;
    int*   rowptrP  = (int*)(W + o);   o += n + 1;
    int*   rowptrN  = (int*)(W + o);   o += n + 1;
    int*   binCntP  = (int*)(W + o);   o += nbin;
    int*   binCntN  = (int*)(W + o);   o += nbin;
    int*   binBaseP = (int*)(W + o);   o += nbin + 1;
    int*   binBaseN = (int*)(W + o);   o += nbin + 1;
    int*   gCur     = (int*)(W + o);   o += nbin;
    int*   esrcP    = (int*)(W + o);   o += Ep;
    int*   esrcN    = (int*)(W + o);   o += En;
    float* RDEN     = (float*)(W + o); o += 4 * (size_t)n;
    o = (o + 3) & ~(size_t)3;
    __half* FH      = (__half*)(W + o); o += 32 * (size_t)n;   // fp16 rows
    float* WGT      = (float*)(W + o);  o += (size_t)Ep + En;  // per-edge weights
    o = (o + 3) & ~(size_t)3;
    float* AGG      = (float*)(W + o);  o += 128 * (size_t)n;
    int*   binned   = (int*)AGG;   // CSR-build scratch aliases AGG

    const int B = 256;
    const int aggBlocks = (2 * n + 3) / 4;
    auto gcap = [](long t, int b) { long g = (t + b - 1) / b; return (int)(g < 2048 ? g : 2048); };

    // ---------------- CSR build (binned; reused by both layers) ------------
    hipMemsetAsync(binCntP, 0, (size_t)nbin * sizeof(int), stream);
    hipMemsetAsync(binCntN, 0, (size_t)nbin * sizeof(int), stream);
    bin_hist_kernel<<<gcap(Ep, B), B, 0, stream>>>(pd, Ep, binCntP, nbin);
    bin_hist_kernel<<<gcap(En, B), B, 0, stream>>>(nd, En, binCntN, nbin);

    scan_bins_kernel<<<1, 256, 0, stream>>>(binCntP, nbin, binBaseP, gCur, rowptrP, n, Ep);
    bin_scatter_kernel<<<(Ep + 4095) / 4096, 256, 0, stream>>>(ps, pd, Ep, binBaseP, gCur, binned, nbin);
    bin_finalize_kernel<<<nbin, 256, 0, stream>>>(binned, binBaseP, rowptrP, esrcP, n);

    scan_bins_kernel<<<1, 256, 0, stream>>>(binCntN, nbin, binBaseN, gCur, rowptrN, n, En);
    bin_scatter_kernel<<<(En + 4095) / 4096, 256, 0, stream>>>(ns, nd, En, binBaseN, gCur, binned, nbin);
    bin_finalize_kernel<<<nbin, 256, 0, stream>>>(binned, binBaseN, rowptrN, esrcN, n);

    // ---------------- Layer 1 ----------------
    scalars1_kernel<<<512, B, 0, stream>>>(x, a1b, a1u, S, FH, n);
    wgt1_kernel<<<nbin, 1024, 0, stream>>>(esrcP, binBaseP, esrcN, binBaseN, S,
                                           WGT, WGT + Ep, RDEN, RDEN + n, n);
    float* aggP = AGG;
    float* aggN = AGG + 64 * (size_t)n;
    agg64_kernel<<<aggBlocks, 256, 0, stream>>>(
        rowptrP, esrcP, WGT,      RDEN,     aggP,
        rowptrN, esrcN, WGT + Ep, RDEN + n, aggN,
        FH, n);
    mlp1_kernel<<<2048, B, 0, stream>>>(aggP, aggN, x, W1b, b1b, W1u, b1u, out, n);

    // ---------------- Layer 2 ----------------
    scalars2_kernel<<<512, B, 0, stream>>>(out, a2b, a2u, S, FH, n);
    wgt2_kernel<<<nbin, 1024, 0, stream>>>(esrcP, binBaseP, esrcN, binBaseN, S,
                                           (unsigned*)WGT, (unsigned*)WGT + Ep,
                                           RDEN, RDEN + n, RDEN + 2 * (size_t)n, RDEN + 3 * (size_t)n, n);
    float* aggBP = AGG;
    float* aggBN = AGG + 32 * (size_t)n;
    float* aggUP = AGG + 64 * (size_t)n;
    float* aggUN = AGG + 96 * (size_t)n;
    agg32pair_kernel<<<aggBlocks, 256, 0, stream>>>(
        rowptrP, esrcP, (unsigned*)WGT,      RDEN,                 RDEN + n,             aggBP, aggUP,
        rowptrN, esrcN, (unsigned*)WGT + Ep, RDEN + 2 * (size_t)n, RDEN + 3 * (size_t)n, aggUN, aggBN,
        FH, n);
    mlp2_kernel<<<2048, B, 0, stream>>>(aggBP, aggBN, aggUP, aggUN,
                                        W2b, b2b, W2u, b2u, out, n);
}

// Round 7
// 575.709 us; speedup vs baseline: 1.0241x; 1.0241x over previous
//
#include <hip/hip_runtime.h>
#include <hip/hip_fp16.h>
#include <math.h>

// ---------------------------------------------------------------------------
// SNEA, fully fused pipeline:
//   CSR build: binned counting sort (bin = dst>>9), packed recs src<<9|dstLocal.
//   scalars1: layer-1 score projections + fp16 copy of x (XH).
//   wgt1:     per-edge layer-1 weights (f32) + rden per node (LDS per bin).
//   layer1_fused: per-wave gather (8 edges in flight, fp16 rows, f32 accum)
//     -> shfl reduce -> normalized agg row in per-wave LDS -> 128x32 MLP half
//     (fp16 transposed weights in LDS, float4 broadcasts) -> tanh -> writes
//     zh fp16 + the 4 layer-2 score dots for its z-half. No f32 z, no mlp1.
//   wgt2:     per-edge layer-2 weight pairs (packed half2) + 4x rden.
//   agg32pair: paired gather over zh -> packed fp16 AGGH[n][128] (bp|bn|up|un).
//   mlp2:     [96->32]x2 MLP from AGGH+zh (fp16 weights in LDS) -> tanh -> out.
// No segment-max anywhere: scores ~N(0,1), unstabilized exp is f32-safe and
// mathematically identical to the max-subtracted softmax.
// ---------------------------------------------------------------------------

#define BIN_SHIFT 9
#define BIN_SPAN  512
#define NBIN_MAX  256          // n <= 131072; src fits 23 bits

// ----------------------------- CSR build ----------------------------------

__global__ __launch_bounds__(256) void bin_hist_kernel(const int* __restrict__ dst, int E,
                                                       int* __restrict__ binCnt, int nbin) {
    __shared__ int lc[NBIN_MAX];
    if (threadIdx.x < NBIN_MAX) lc[threadIdx.x] = 0;
    __syncthreads();
    int i = blockIdx.x * blockDim.x + threadIdx.x;
    int stride = gridDim.x * blockDim.x;
    for (; i < E; i += stride) atomicAdd(&lc[dst[i] >> BIN_SHIFT], 1);
    __syncthreads();
    if (threadIdx.x < nbin && lc[threadIdx.x]) atomicAdd(&binCnt[threadIdx.x], lc[threadIdx.x]);
}

__global__ __launch_bounds__(256) void scan_bins_kernel(const int* __restrict__ binCnt, int nbin,
                                                        int* __restrict__ binBase,
                                                        int* __restrict__ gCursor,
                                                        int* __restrict__ rowptr, int n, int E) {
    __shared__ int sd[256];
    int tid = threadIdx.x;
    int v = (tid < nbin) ? binCnt[tid] : 0;
    sd[tid] = v; __syncthreads();
    for (int off = 1; off < 256; off <<= 1) {
        int t = (tid >= off) ? sd[tid - off] : 0;
        __syncthreads();
        sd[tid] += t;
        __syncthreads();
    }
    if (tid < nbin) { binBase[tid] = sd[tid] - v; gCursor[tid] = 0; }
    if (tid == nbin - 1) binBase[nbin] = sd[tid];
    if (tid == 0) rowptr[n] = E;
}

__global__ __launch_bounds__(256) void bin_scatter_kernel(
        const int* __restrict__ src, const int* __restrict__ dst, int E,
        const int* __restrict__ binBase, int* __restrict__ gCursor,
        int* __restrict__ binned, int nbin) {
    __shared__ int lc[NBIN_MAX];
    __shared__ int lbase[NBIN_MAX];
    if (threadIdx.x < NBIN_MAX) lc[threadIdx.x] = 0;
    __syncthreads();
    int base0 = blockIdx.x * 4096 + threadIdx.x * 16;
    int rank[16], bn[16];
    #pragma unroll
    for (int k = 0; k < 16; ++k) {
        int i = base0 + k;
        if (i < E) {
            int b = dst[i] >> BIN_SHIFT;
            bn[k] = b;
            rank[k] = atomicAdd(&lc[b], 1);
        }
    }
    __syncthreads();
    if (threadIdx.x < nbin && lc[threadIdx.x])
        lbase[threadIdx.x] = atomicAdd(&gCursor[threadIdx.x], lc[threadIdx.x]);
    __syncthreads();
    #pragma unroll
    for (int k = 0; k < 16; ++k) {
        int i = base0 + k;
        if (i < E) {
            int b = bn[k];
            int pos = binBase[b] + lbase[b] + rank[k];
            binned[pos] = (src[i] << BIN_SHIFT) | (dst[i] & (BIN_SPAN - 1));
        }
    }
}

__global__ __launch_bounds__(256) void bin_finalize_kernel(
        const int* __restrict__ binned, const int* __restrict__ binBase,
        int* __restrict__ rowptr, int* __restrict__ esrc, int n) {
    __shared__ int hist[BIN_SPAN];
    __shared__ int curs[BIN_SPAN];
    __shared__ int psum[256];
    int b = blockIdx.x, tid = threadIdx.x;
    int lo = binBase[b], hi = binBase[b + 1];
    int nodeBase = b << BIN_SHIFT;
    hist[tid] = 0; hist[tid + 256] = 0;
    __syncthreads();
    for (int i = lo + tid; i < hi; i += 256)
        atomicAdd(&hist[binned[i] & (BIN_SPAN - 1)], 1);
    __syncthreads();
    int a0 = hist[2 * tid], a1 = hist[2 * tid + 1];
    int ps = a0 + a1;
    psum[tid] = ps; __syncthreads();
    for (int off = 1; off < 256; off <<= 1) {
        int t = (tid >= off) ? psum[tid - off] : 0;
        __syncthreads();
        psum[tid] += t;
        __syncthreads();
    }
    int excl = psum[tid] - ps;
    curs[2 * tid] = excl;
    curs[2 * tid + 1] = excl + a0;
    {
        int idx0 = nodeBase + 2 * tid;
        if (idx0 <= n)     rowptr[idx0]     = lo + excl;
        if (idx0 + 1 <= n) rowptr[idx0 + 1] = lo + excl + a0;
    }
    __syncthreads();
    for (int i = lo + tid; i < hi; i += 256) {
        int rec = binned[i];
        int slot = lo + atomicAdd(&curs[rec & (BIN_SPAN - 1)], 1);
        esrc[slot] = rec;      // keep packed
    }
}

// --------------------------- scalars (layer 1) ------------------------------

__global__ __launch_bounds__(256) void scalars1_kernel(
        const float* __restrict__ x,
        const float* __restrict__ a1b, const float* __restrict__ a1u,
        float* __restrict__ S, __half* __restrict__ xh, int n) {
    __shared__ float sA[256];
    for (int k = threadIdx.x; k < 256; k += blockDim.x)
        sA[k] = (k < 128) ? a1b[k] : a1u[k - 128];
    __syncthreads();
    int grp = threadIdx.x >> 4, l = threadIdx.x & 15;
    for (int row = blockIdx.x * 16 + grp; row < n; row += gridDim.x * 16) {
        const float4 v = *(const float4*)(x + (size_t)row * 64 + l * 4);
        __half2 h0 = __floats2half2_rn(v.x, v.y);
        __half2 h1 = __floats2half2_rn(v.z, v.w);
        uint2 pk = make_uint2(*(unsigned*)&h0, *(unsigned*)&h1);
        *(uint2*)(xh + (size_t)row * 64 + l * 4) = pk;
        const float4 A0 = *(const float4*)(sA + l * 4);
        const float4 A1 = *(const float4*)(sA + 64 + l * 4);
        const float4 A2 = *(const float4*)(sA + 128 + l * 4);
        const float4 A3 = *(const float4*)(sA + 192 + l * 4);
        float p0 = fmaf(v.x, A0.x, fmaf(v.y, A0.y, fmaf(v.z, A0.z, v.w * A0.w)));
        float p1 = fmaf(v.x, A1.x, fmaf(v.y, A1.y, fmaf(v.z, A1.z, v.w * A1.w)));
        float p2 = fmaf(v.x, A2.x, fmaf(v.y, A2.y, fmaf(v.z, A2.z, v.w * A2.w)));
        float p3 = fmaf(v.x, A3.x, fmaf(v.y, A3.y, fmaf(v.z, A3.z, v.w * A3.w)));
        #pragma unroll
        for (int off = 1; off < 16; off <<= 1) {
            p0 += __shfl_xor(p0, off);
            p1 += __shfl_xor(p1, off);
            p2 += __shfl_xor(p2, off);
            p3 += __shfl_xor(p3, off);
        }
        if (l == 0) {
            S[row] = p0;
            S[(size_t)n + row] = p1;
            S[2 * (size_t)n + row] = p2;
            S[3 * (size_t)n + row] = p3;
        }
    }
}

// ----------------------- per-edge weights + den ----------------------------

__global__ __launch_bounds__(1024) void wgt1_kernel(
        const int* __restrict__ esrcP, const int* __restrict__ binBaseP,
        const int* __restrict__ esrcN, const int* __restrict__ binBaseN,
        const float* __restrict__ S,
        float* __restrict__ wgtP, float* __restrict__ wgtN,
        float* __restrict__ rdenP, float* __restrict__ rdenN, int n) {
    __shared__ float dP[BIN_SPAN], dN[BIN_SPAN];
    int b = blockIdx.x, tid = threadIdx.x;
    if (tid < BIN_SPAN) { dP[tid] = 0.f; dN[tid] = 0.f; }
    __syncthreads();
    int nodeBase = b << BIN_SHIFT;
    const float* siP = S;                     const float* sjP = S + (size_t)n;
    const float* siN = S + 2 * (size_t)n;     const float* sjN = S + 3 * (size_t)n;
    for (int i = binBaseP[b] + tid, hi = binBaseP[b + 1]; i < hi; i += 1024) {
        int rec = esrcP[i];
        int src = (int)((unsigned)rec >> BIN_SHIFT);
        int dl  = rec & (BIN_SPAN - 1);
        float w = __expf(siP[nodeBase + dl] + sjP[src]);
        wgtP[i] = w;
        atomicAdd(&dP[dl], w);
    }
    for (int i = binBaseN[b] + tid, hi = binBaseN[b + 1]; i < hi; i += 1024) {
        int rec = esrcN[i];
        int src = (int)((unsigned)rec >> BIN_SHIFT);
        int dl  = rec & (BIN_SPAN - 1);
        float w = __expf(siN[nodeBase + dl] + sjN[src]);
        wgtN[i] = w;
        atomicAdd(&dN[dl], w);
    }
    __syncthreads();
    if (tid < BIN_SPAN) {
        int node = nodeBase + tid;
        if (node < n) {
            rdenP[node] = 1.0f / fmaxf(dP[tid], 1e-16f);
            rdenN[node] = 1.0f / fmaxf(dN[tid], 1e-16f);
        }
    }
}

// pos: L=bp(S0,S1) H=up(S4,S5).  neg: L=un(S6,S7) H=bn(S2,S3).
__global__ __launch_bounds__(1024) void wgt2_kernel(
        const int* __restrict__ esrcP, const int* __restrict__ binBaseP,
        const int* __restrict__ esrcN, const int* __restrict__ binBaseN,
        const float* __restrict__ S,
        unsigned* __restrict__ wgtP, unsigned* __restrict__ wgtN,
        float* __restrict__ rdenPL, float* __restrict__ rdenPH,
        float* __restrict__ rdenNL, float* __restrict__ rdenNH, int n) {
    __shared__ float dPL[BIN_SPAN], dPH[BIN_SPAN], dNL[BIN_SPAN], dNH[BIN_SPAN];
    int b = blockIdx.x, tid = threadIdx.x;
    if (tid < BIN_SPAN) { dPL[tid] = 0.f; dPH[tid] = 0.f; dNL[tid] = 0.f; dNH[tid] = 0.f; }
    __syncthreads();
    int nodeBase = b << BIN_SHIFT;
    const float* S0 = S;                   const float* S1 = S + (size_t)n;
    const float* S2 = S + 2 * (size_t)n;   const float* S3 = S + 3 * (size_t)n;
    const float* S4 = S + 4 * (size_t)n;   const float* S5 = S + 5 * (size_t)n;
    const float* S6 = S + 6 * (size_t)n;   const float* S7 = S + 7 * (size_t)n;
    for (int i = binBaseP[b] + tid, hi = binBaseP[b + 1]; i < hi; i += 1024) {
        int rec = esrcP[i];
        int src = (int)((unsigned)rec >> BIN_SHIFT);
        int dl  = rec & (BIN_SPAN - 1);
        float wL = __expf(S0[nodeBase + dl] + S1[src]);   // bp
        float wH = __expf(S4[nodeBase + dl] + S5[src]);   // up
        __half2 h = __floats2half2_rn(wL, wH);
        wgtP[i] = *(unsigned*)&h;
        atomicAdd(&dPL[dl], wL);
        atomicAdd(&dPH[dl], wH);
    }
    for (int i = binBaseN[b] + tid, hi = binBaseN[b + 1]; i < hi; i += 1024) {
        int rec = esrcN[i];
        int src = (int)((unsigned)rec >> BIN_SHIFT);
        int dl  = rec & (BIN_SPAN - 1);
        float wL = __expf(S6[nodeBase + dl] + S7[src]);   // un
        float wH = __expf(S2[nodeBase + dl] + S3[src]);   // bn
        __half2 h = __floats2half2_rn(wL, wH);
        wgtN[i] = *(unsigned*)&h;
        atomicAdd(&dNL[dl], wL);
        atomicAdd(&dNH[dl], wH);
    }
    __syncthreads();
    if (tid < BIN_SPAN) {
        int node = nodeBase + tid;
        if (node < n) {
            rdenPL[node] = 1.0f / fmaxf(dPL[tid], 1e-16f);
            rdenPH[node] = 1.0f / fmaxf(dPH[tid], 1e-16f);
            rdenNL[node] = 1.0f / fmaxf(dNL[tid], 1e-16f);
            rdenNH[node] = 1.0f / fmaxf(dNH[tid], 1e-16f);
        }
    }
}

// ----------------- layer 1: fused gather + MLP + tanh + scores ------------

#define W1PAD 132   // halves; col*66 dwords, 66%32=2 -> ~2-way (free) banks

__global__ __launch_bounds__(256) void layer1_fused_kernel(
        const int* __restrict__ rpA, const int* __restrict__ esA,
        const float* __restrict__ wA, const float* __restrict__ rdA,
        const int* __restrict__ rpB, const int* __restrict__ esB,
        const float* __restrict__ wB, const float* __restrict__ rdB,
        const __half* __restrict__ xh, const float* __restrict__ x,
        const float* __restrict__ W1b, const float* __restrict__ b1b,
        const float* __restrict__ W1u, const float* __restrict__ b1u,
        const float* __restrict__ a2b, const float* __restrict__ a2u,
        __half* __restrict__ zh, float* __restrict__ S, int n) {
    __shared__ __half sW[2][32][W1PAD];
    __shared__ float sA2[128];
    __shared__ float sB1[2][32];
    __shared__ alignas(16) float sIn[4][64];
    __shared__ alignas(16) float sX[4][64];
    // stage weights (transposed, fp16), biases, alpha2
    for (int i = threadIdx.x; i < 8192; i += 256) {
        int fam = i >> 12, r = i & 4095;
        int col = r & 31, k = r >> 5;
        sW[fam][col][k] = __float2half(fam ? W1u[r] : W1b[r]);
    }
    for (int i = threadIdx.x; i < 128; i += 256)
        sA2[i] = (i < 64) ? a2b[i] : a2u[i - 64];
    if (threadIdx.x < 64) {
        int f = threadIdx.x >> 5, c = threadIdx.x & 31;
        sB1[f][c] = f ? b1u[c] : b1b[c];
    }
    __syncthreads();

    int w = threadIdx.x >> 6, lane = threadIdx.x & 63;
    int g3 = lane >> 3, q8 = lane & 7;
    int h = lane >> 5, col = lane & 31;
    int G = (2 * n + 3) >> 2;
    for (int grp = blockIdx.x; grp < G; grp += gridDim.x) {
        int idx = grp * 4 + w;
        if (idx >= 2 * n) continue;
        bool second = idx >= n;
        int node = second ? idx - n : idx;
        const int*   rp = second ? rpB : rpA;
        const int*   es = second ? esB : esA;
        const float* wg = second ? wB : wA;
        float r = (second ? rdB : rdA)[node];

        int start = rp[node], len = rp[node + 1] - start;
        float a0=0,a1=0,a2=0,a3=0,a4=0,a5=0,a6=0,a7=0;
        for (int cb = 0; cb < len; cb += 64) {
            int t = cb + lane;
            float wv = 0.f; int sr = 0;
            if (t < len) { wv = wg[start + t]; sr = es[start + t]; }
            int cl = len - cb; if (cl > 64) cl = 64;
            #pragma unroll 2
            for (int u = 0; u < cl; u += 8) {
                int e = u + g3;
                float wt = __shfl(wv, e);
                int   sp = __shfl(sr, e);
                if (e < cl) {
                    size_t st = (size_t)((unsigned)sp >> BIN_SHIFT);
                    const uint4 pk = *(const uint4*)(xh + st * 64 + q8 * 8);
                    float2 f0 = __half22float2(*(const __half2*)&pk.x);
                    float2 f1 = __half22float2(*(const __half2*)&pk.y);
                    float2 f2 = __half22float2(*(const __half2*)&pk.z);
                    float2 f3 = __half22float2(*(const __half2*)&pk.w);
                    a0 = fmaf(wt, f0.x, a0); a1 = fmaf(wt, f0.y, a1);
                    a2 = fmaf(wt, f1.x, a2); a3 = fmaf(wt, f1.y, a3);
                    a4 = fmaf(wt, f2.x, a4); a5 = fmaf(wt, f2.y, a5);
                    a6 = fmaf(wt, f3.x, a6); a7 = fmaf(wt, f3.y, a7);
                }
            }
        }
        #pragma unroll
        for (int off = 8; off <= 32; off <<= 1) {
            a0 += __shfl_xor(a0, off); a1 += __shfl_xor(a1, off);
            a2 += __shfl_xor(a2, off); a3 += __shfl_xor(a3, off);
            a4 += __shfl_xor(a4, off); a5 += __shfl_xor(a5, off);
            a6 += __shfl_xor(a6, off); a7 += __shfl_xor(a7, off);
        }
        // park normalized agg row + x row in per-wave LDS (same-wave, no barrier)
        if (g3 == 0) {
            *(float4*)(&sIn[w][q8 * 8])     = make_float4(a0 * r, a1 * r, a2 * r, a3 * r);
            *(float4*)(&sIn[w][q8 * 8 + 4]) = make_float4(a4 * r, a5 * r, a6 * r, a7 * r);
        }
        sX[w][lane] = x[(size_t)node * 64 + lane];

        // MLP half: lane (h,col): h=0 sums agg part (W rows 0-63), h=1 x part.
        const float* inb = h ? sX[w] : sIn[w];
        const __half* wr = &sW[second ? 1 : 0][col][h * 64];
        float acc = 0.f;
        #pragma unroll
        for (int t = 0; t < 16; ++t) {
            float4 iv = *(const float4*)(inb + 4 * t);
            uint2 wp = *(const uint2*)(wr + 4 * t);
            float2 w0 = __half22float2(*(const __half2*)&wp.x);
            float2 w1 = __half22float2(*(const __half2*)&wp.y);
            acc = fmaf(iv.x, w0.x, fmaf(iv.y, w0.y, fmaf(iv.z, w1.x, fmaf(iv.w, w1.y, acc))));
        }
        acc += __shfl_xor(acc, 32);
        float zv = tanhf(acc + sB1[second ? 1 : 0][col]);
        if (h == 0) zh[(size_t)node * 64 + (second ? 32 : 0) + col] = __float2half(zv);
        // layer-2 score dots for this z-half
        float t0 = zv * sA2[h * 32 + col];        // vs a2b half h
        float t1 = zv * sA2[64 + h * 32 + col];   // vs a2u half h
        #pragma unroll
        for (int off = 1; off < 32; off <<= 1) {
            t0 += __shfl_xor(t0, off);
            t1 += __shfl_xor(t1, off);
        }
        if (col == 0) {
            // pos(zb): t0->S0/S1, t1->S6/S7 ; neg(zu): t0->S2/S3, t1->S4/S5
            size_t b0 = second ? 2 : 0, b1 = second ? 4 : 6;
            S[(b0 + h) * (size_t)n + node] = t0;
            S[(b1 + h) * (size_t)n + node] = t1;
        }
    }
}

// ------------------- layer 2 aggregation (paired gather) -------------------

// AGGH row layout per node: [bp(32) | bn(32) | up(32) | un(32)] fp16.
__global__ __launch_bounds__(256) void agg32pair_kernel(
        const int* __restrict__ rpA, const int* __restrict__ esA,
        const unsigned* __restrict__ wA,
        const float* __restrict__ rdLA, const float* __restrict__ rdHA,
        const int* __restrict__ rpB, const int* __restrict__ esB,
        const unsigned* __restrict__ wB,
        const float* __restrict__ rdLB, const float* __restrict__ rdHB,
        const __half* __restrict__ zh, __half* __restrict__ AGGH, int n) {
    int w = threadIdx.x >> 6, lane = threadIdx.x & 63;
    int idx = blockIdx.x * 4 + w;
    if (idx >= 2 * n) return;
    bool second = idx >= n;
    int node = second ? idx - n : idx;
    const int*      rp  = second ? rpB  : rpA;
    const int*      es  = second ? esB  : esA;
    const unsigned* wg  = second ? wB   : wA;
    const float*    rdL = second ? rdLB : rdLA;
    const float*    rdH = second ? rdHB : rdHA;

    int start = rp[node], len = rp[node + 1] - start;
    int g3 = lane >> 3, q8 = lane & 7;
    bool lowf = q8 < 4;
    float a0=0,a1=0,a2=0,a3=0,a4=0,a5=0,a6=0,a7=0;

    for (int cb = 0; cb < len; cb += 64) {
        int t = cb + lane;
        unsigned wv = 0; int sr = 0;
        if (t < len) { wv = wg[start + t]; sr = es[start + t]; }
        int cl = len - cb; if (cl > 64) cl = 64;
        #pragma unroll 2
        for (int u = 0; u < cl; u += 8) {
            int e = u + g3;
            unsigned wp = (unsigned)__shfl((int)wv, e);
            int      sp = __shfl(sr, e);
            if (e < cl) {
                float2 wf = __half22float2(*(const __half2*)&wp);
                float wt = lowf ? wf.x : wf.y;
                size_t st = (size_t)((unsigned)sp >> BIN_SHIFT);
                const uint4 pk = *(const uint4*)(zh + st * 64 + q8 * 8);
                float2 f0 = __half22float2(*(const __half2*)&pk.x);
                float2 f1 = __half22float2(*(const __half2*)&pk.y);
                float2 f2 = __half22float2(*(const __half2*)&pk.z);
                float2 f3 = __half22float2(*(const __half2*)&pk.w);
                a0 = fmaf(wt, f0.x, a0); a1 = fmaf(wt, f0.y, a1);
                a2 = fmaf(wt, f1.x, a2); a3 = fmaf(wt, f1.y, a3);
                a4 = fmaf(wt, f2.x, a4); a5 = fmaf(wt, f2.y, a5);
                a6 = fmaf(wt, f3.x, a6); a7 = fmaf(wt, f3.y, a7);
            }
        }
    }
    #pragma unroll
    for (int off = 8; off <= 32; off <<= 1) {
        a0 += __shfl_xor(a0, off); a1 += __shfl_xor(a1, off);
        a2 += __shfl_xor(a2, off); a3 += __shfl_xor(a3, off);
        a4 += __shfl_xor(a4, off); a5 += __shfl_xor(a5, off);
        a6 += __shfl_xor(a6, off); a7 += __shfl_xor(a7, off);
    }
    if (g3 == 0) {
        float r = lowf ? rdL[node] : rdH[node];
        __half2 p0 = __floats2half2_rn(a0 * r, a1 * r);
        __half2 p1 = __floats2half2_rn(a2 * r, a3 * r);
        __half2 p2 = __floats2half2_rn(a4 * r, a5 * r);
        __half2 p3 = __floats2half2_rn(a6 * r, a7 * r);
        uint4 pk = make_uint4(*(unsigned*)&p0, *(unsigned*)&p1, *(unsigned*)&p2, *(unsigned*)&p3);
        // pos: L=bp->0, H=up->64 ; neg: L=un->96, H=bn->32
        int base = second ? (lowf ? 96 : 32) : (lowf ? 0 : 64);
        *(uint4*)(AGGH + (size_t)node * 128 + base + (q8 & 3) * 8) = pk;
    }
}

// ------------------------------- MLP 2 -------------------------------------

#define W2PAD 108   // halves; col*54 dwords, 54%32=22, gcd(22,32)=2 -> ~2-way

__global__ __launch_bounds__(256) void mlp2_kernel(
        const __half* __restrict__ AGGH, const __half* __restrict__ zh,
        const float* __restrict__ W2b, const float* __restrict__ b2b,
        const float* __restrict__ W2u, const float* __restrict__ b2u,
        float* __restrict__ out, int n) {
    __shared__ __half sW[2][32][W2PAD];
    __shared__ float sB[2][32];
    __shared__ alignas(16) float sIn[4][2][96];
    for (int i = threadIdx.x; i < 6144; i += 256) {
        int fam = (i >= 3072), r = fam ? i - 3072 : i;
        int col = r & 31, k = r >> 5;
        sW[fam][col][k] = __float2half(fam ? W2u[r] : W2b[r]);
    }
    if (threadIdx.x < 64) {
        int f = threadIdx.x >> 5, c = threadIdx.x & 31;
        sB[f][c] = f ? b2u[c] : b2b[c];
    }
    __syncthreads();

    int w = threadIdx.x >> 6, lane = threadIdx.x & 63;
    int f = lane >> 5, col = lane & 31;
    int G = (n + 3) >> 2;
    for (int grp = blockIdx.x; grp < G; grp += gridDim.x) {
        int node = grp * 4 + w;
        if (node >= n) continue;
        // stage [bp|bn|zb] and [up|un|zu] as f32 (same-wave, no barrier)
        if (lane < 32) {
            int m = lane * 4;                      // 0..124 within AGGH row
            uint2 v = *(const uint2*)(AGGH + (size_t)node * 128 + m);
            float2 f0 = __half22float2(*(const __half2*)&v.x);
            float2 f1 = __half22float2(*(const __half2*)&v.y);
            float* dp = &sIn[w][m >> 6][m & 63];
            *(float4*)dp = make_float4(f0.x, f0.y, f1.x, f1.y);
        } else {
            int j = (lane - 32) * 2;               // 0..62 within zh row
            unsigned v = *(const unsigned*)(zh + (size_t)node * 64 + j);
            float2 fz = __half22float2(*(const __half2*)&v);
            float* dp = &sIn[w][j >> 5][64 + (j & 31)];
            dp[0] = fz.x; dp[1] = fz.y;
        }
        const float* in = sIn[w][f];
        const __half* wr = &sW[f][col][0];
        float acc = sB[f][col];
        #pragma unroll
        for (int t = 0; t < 24; ++t) {
            float4 iv = *(const float4*)(in + 4 * t);
            uint2 wp = *(const uint2*)(wr + 4 * t);
            float2 w0 = __half22float2(*(const __half2*)&wp.x);
            float2 w1 = __half22float2(*(const __half2*)&wp.y);
            acc = fmaf(iv.x, w0.x, fmaf(iv.y, w0.y, fmaf(iv.z, w1.x, fmaf(iv.w, w1.y, acc))));
        }
        out[(size_t)node * 64 + f * 32 + col] = tanhf(acc);
    }
}

// ------------------------------ launcher -----------------------------------

extern "C" void kernel_launch(void* const* d_in, const int* in_sizes, int n_in,
                              void* d_out, int out_size, void* d_ws, size_t ws_size,
                              hipStream_t stream) {
    const float* x   = (const float*)d_in[0];
    const int*   pos = (const int*)d_in[1];
    const int*   neg = (const int*)d_in[2];
    const float* a1b = (const float*)d_in[3];
    const float* a1u = (const float*)d_in[4];
    const float* W1b = (const float*)d_in[5];
    const float* b1b = (const float*)d_in[6];
    const float* W1u = (const float*)d_in[7];
    const float* b1u = (const float*)d_in[8];
    const float* a2b = (const float*)d_in[9];
    const float* a2u = (const float*)d_in[10];
    const float* W2b = (const float*)d_in[11];
    const float* b2b = (const float*)d_in[12];
    const float* W2u = (const float*)d_in[13];
    const float* b2u = (const float*)d_in[14];
    float* out = (float*)d_out;

    const int n  = in_sizes[0] / 64;
    const int Ep = in_sizes[1] / 2;
    const int En = in_sizes[2] / 2;
    const int* ps = pos;  const int* pd = pos + Ep;
    const int* ns = neg;  const int* nd = neg + En;
    const int nbin = (n + BIN_SPAN - 1) >> BIN_SHIFT;

    // ws layout (4-byte words)
    unsigned* W = (unsigned*)d_ws;
    size_t o = 0;
    float* S        = (float*)(W + o); o += 8 * (size_t)n;
    int*   rowptrP  = (int*)(W + o);   o += n + 1;
    int*   rowptrN  = (int*)(W + o);   o += n + 1;
    int*   binCntP  = (int*)(W + o);   o += nbin;
    int*   binCntN  = (int*)(W + o);   o += nbin;
    int*   binBaseP = (int*)(W + o);   o += nbin + 1;
    int*   binBaseN = (int*)(W + o);   o += nbin + 1;
    int*   gCur     = (int*)(W + o);   o += nbin;
    int*   esrcP    = (int*)(W + o);   o += Ep;
    int*   esrcN    = (int*)(W + o);   o += En;
    float* RDEN     = (float*)(W + o); o += 4 * (size_t)n;
    o = (o + 3) & ~(size_t)3;
    __half* XH      = (__half*)(W + o); o += 32 * (size_t)n;   // x rows fp16
    __half* ZH      = (__half*)(W + o); o += 32 * (size_t)n;   // z rows fp16
    float* WGT      = (float*)(W + o);  o += (size_t)Ep + En;
    o = (o + 3) & ~(size_t)3;
    __half* AGGH    = (__half*)(W + o); o += 64 * (size_t)n;   // [n][128] fp16
    int*   binned   = (int*)AGGH;   // CSR-build scratch aliases AGGH

    const int B = 256;
    const int aggBlocks = (2 * n + 3) / 4;
    auto gcap = [](long t, int b) { long g = (t + b - 1) / b; return (int)(g < 2048 ? g : 2048); };

    // ---------------- CSR build ----------------
    hipMemsetAsync(binCntP, 0, (size_t)nbin * sizeof(int), stream);
    hipMemsetAsync(binCntN, 0, (size_t)nbin * sizeof(int), stream);
    bin_hist_kernel<<<gcap(Ep, B), B, 0, stream>>>(pd, Ep, binCntP, nbin);
    bin_hist_kernel<<<gcap(En, B), B, 0, stream>>>(nd, En, binCntN, nbin);

    scan_bins_kernel<<<1, 256, 0, stream>>>(binCntP, nbin, binBaseP, gCur, rowptrP, n, Ep);
    bin_scatter_kernel<<<(Ep + 4095) / 4096, 256, 0, stream>>>(ps, pd, Ep, binBaseP, gCur, binned, nbin);
    bin_finalize_kernel<<<nbin, 256, 0, stream>>>(binned, binBaseP, rowptrP, esrcP, n);

    scan_bins_kernel<<<1, 256, 0, stream>>>(binCntN, nbin, binBaseN, gCur, rowptrN, n, En);
    bin_scatter_kernel<<<(En + 4095) / 4096, 256, 0, stream>>>(ns, nd, En, binBaseN, gCur, binned, nbin);
    bin_finalize_kernel<<<nbin, 256, 0, stream>>>(binned, binBaseN, rowptrN, esrcN, n);

    // ---------------- Layer 1 (fused) ----------------
    scalars1_kernel<<<512, B, 0, stream>>>(x, a1b, a1u, S, XH, n);
    wgt1_kernel<<<nbin, 1024, 0, stream>>>(esrcP, binBaseP, esrcN, binBaseN, S,
                                           WGT, WGT + Ep, RDEN, RDEN + n, n);
    layer1_fused_kernel<<<8192, B, 0, stream>>>(
        rowptrP, esrcP, WGT,      RDEN,
        rowptrN, esrcN, WGT + Ep, RDEN + n,
        XH, x, W1b, b1b, W1u, b1u, a2b, a2u, ZH, S, n);

    // ---------------- Layer 2 ----------------
    wgt2_kernel<<<nbin, 1024, 0, stream>>>(esrcP, binBaseP, esrcN, binBaseN, S,
                                           (unsigned*)WGT, (unsigned*)WGT + Ep,
                                           RDEN, RDEN + n, RDEN + 2 * (size_t)n, RDEN + 3 * (size_t)n, n);
    agg32pair_kernel<<<aggBlocks, 256, 0, stream>>>(
        rowptrP, esrcP, (unsigned*)WGT,      RDEN,                 RDEN + n,
        rowptrN, esrcN, (unsigned*)WGT + Ep, RDEN + 2 * (size_t)n, RDEN + 3 * (size_t)n,
        ZH, AGGH, n);
    mlp2_kernel<<<4096, B, 0, stream>>>(AGGH, ZH, W2b, b2b, W2u, b2u, out, n);
}

// Round 8
// 547.779 us; speedup vs baseline: 1.0763x; 1.0510x over previous
//
#include <hip/hip_runtime.h>
#include <hip/hip_fp16.h>
#include <math.h>

// ---------------------------------------------------------------------------
// SNEA pipeline (unfused gather / MLP, fp16 data paths):
//   CSR build: binned counting sort (bin = dst>>9), packed recs src<<9|dstLocal.
//   scalars1: layer-1 score projections + fp16 copy of x (XH).
//   wgt1:     per-edge layer-1 weights (f32) + rden per node (LDS per bin).
//   agg64:    pure gather (8 edges in flight, fp16 rows, f32 accum) ->
//             normalized fp16 AGGH1[n][128] = [aggP|aggN].
//   mlp1f:    128->32 x2 MLP (fp16 transposed weights in LDS, f32 broadcast
//             inputs from AGGH1+XH) -> tanh -> ZH fp16 + all 8 layer-2 score
//             dots in-register (no scalars2 kernel, no f32 z anywhere).
//   wgt2:     per-edge layer-2 weight pairs (packed half2) + 4x rden.
//   agg32pair: paired gather over ZH -> fp16 AGGH[n][128] (bp|bn|up|un).
//   mlp2:     [96->32]x2 MLP from AGGH+ZH -> tanh -> out.
// No segment-max anywhere: scores ~N(0,1), unstabilized exp is f32-safe and
// mathematically identical to the max-subtracted softmax.
// ---------------------------------------------------------------------------

#define BIN_SHIFT 9
#define BIN_SPAN  512
#define NBIN_MAX  256          // n <= 131072; src fits 23 bits

// ----------------------------- CSR build ----------------------------------

__global__ __launch_bounds__(256) void bin_hist_kernel(const int* __restrict__ dst, int E,
                                                       int* __restrict__ binCnt, int nbin) {
    __shared__ int lc[NBIN_MAX];
    if (threadIdx.x < NBIN_MAX) lc[threadIdx.x] = 0;
    __syncthreads();
    int i = blockIdx.x * blockDim.x + threadIdx.x;
    int stride = gridDim.x * blockDim.x;
    for (; i < E; i += stride) atomicAdd(&lc[dst[i] >> BIN_SHIFT], 1);
    __syncthreads();
    if (threadIdx.x < nbin && lc[threadIdx.x]) atomicAdd(&binCnt[threadIdx.x], lc[threadIdx.x]);
}

__global__ __launch_bounds__(256) void scan_bins_kernel(const int* __restrict__ binCnt, int nbin,
                                                        int* __restrict__ binBase,
                                                        int* __restrict__ gCursor,
                                                        int* __restrict__ rowptr, int n, int E) {
    __shared__ int sd[256];
    int tid = threadIdx.x;
    int v = (tid < nbin) ? binCnt[tid] : 0;
    sd[tid] = v; __syncthreads();
    for (int off = 1; off < 256; off <<= 1) {
        int t = (tid >= off) ? sd[tid - off] : 0;
        __syncthreads();
        sd[tid] += t;
        __syncthreads();
    }
    if (tid < nbin) { binBase[tid] = sd[tid] - v; gCursor[tid] = 0; }
    if (tid == nbin - 1) binBase[nbin] = sd[tid];
    if (tid == 0) rowptr[n] = E;
}

__global__ __launch_bounds__(256) void bin_scatter_kernel(
        const int* __restrict__ src, const int* __restrict__ dst, int E,
        const int* __restrict__ binBase, int* __restrict__ gCursor,
        int* __restrict__ binned, int nbin) {
    __shared__ int lc[NBIN_MAX];
    __shared__ int lbase[NBIN_MAX];
    if (threadIdx.x < NBIN_MAX) lc[threadIdx.x] = 0;
    __syncthreads();
    int base0 = blockIdx.x * 4096 + threadIdx.x * 16;
    int rank[16], bn[16];
    #pragma unroll
    for (int k = 0; k < 16; ++k) {
        int i = base0 + k;
        if (i < E) {
            int b = dst[i] >> BIN_SHIFT;
            bn[k] = b;
            rank[k] = atomicAdd(&lc[b], 1);
        }
    }
    __syncthreads();
    if (threadIdx.x < nbin && lc[threadIdx.x])
        lbase[threadIdx.x] = atomicAdd(&gCursor[threadIdx.x], lc[threadIdx.x]);
    __syncthreads();
    #pragma unroll
    for (int k = 0; k < 16; ++k) {
        int i = base0 + k;
        if (i < E) {
            int b = bn[k];
            int pos = binBase[b] + lbase[b] + rank[k];
            binned[pos] = (src[i] << BIN_SHIFT) | (dst[i] & (BIN_SPAN - 1));
        }
    }
}

__global__ __launch_bounds__(256) void bin_finalize_kernel(
        const int* __restrict__ binned, const int* __restrict__ binBase,
        int* __restrict__ rowptr, int* __restrict__ esrc, int n) {
    __shared__ int hist[BIN_SPAN];
    __shared__ int curs[BIN_SPAN];
    __shared__ int psum[256];
    int b = blockIdx.x, tid = threadIdx.x;
    int lo = binBase[b], hi = binBase[b + 1];
    int nodeBase = b << BIN_SHIFT;
    hist[tid] = 0; hist[tid + 256] = 0;
    __syncthreads();
    for (int i = lo + tid; i < hi; i += 256)
        atomicAdd(&hist[binned[i] & (BIN_SPAN - 1)], 1);
    __syncthreads();
    int a0 = hist[2 * tid], a1 = hist[2 * tid + 1];
    int ps = a0 + a1;
    psum[tid] = ps; __syncthreads();
    for (int off = 1; off < 256; off <<= 1) {
        int t = (tid >= off) ? psum[tid - off] : 0;
        __syncthreads();
        psum[tid] += t;
        __syncthreads();
    }
    int excl = psum[tid] - ps;
    curs[2 * tid] = excl;
    curs[2 * tid + 1] = excl + a0;
    {
        int idx0 = nodeBase + 2 * tid;
        if (idx0 <= n)     rowptr[idx0]     = lo + excl;
        if (idx0 + 1 <= n) rowptr[idx0 + 1] = lo + excl + a0;
    }
    __syncthreads();
    for (int i = lo + tid; i < hi; i += 256) {
        int rec = binned[i];
        int slot = lo + atomicAdd(&curs[rec & (BIN_SPAN - 1)], 1);
        esrc[slot] = rec;      // keep packed
    }
}

// --------------------------- scalars (layer 1) ------------------------------

__global__ __launch_bounds__(256) void scalars1_kernel(
        const float* __restrict__ x,
        const float* __restrict__ a1b, const float* __restrict__ a1u,
        float* __restrict__ S, __half* __restrict__ xh, int n) {
    __shared__ float sA[256];
    for (int k = threadIdx.x; k < 256; k += blockDim.x)
        sA[k] = (k < 128) ? a1b[k] : a1u[k - 128];
    __syncthreads();
    int grp = threadIdx.x >> 4, l = threadIdx.x & 15;
    for (int row = blockIdx.x * 16 + grp; row < n; row += gridDim.x * 16) {
        const float4 v = *(const float4*)(x + (size_t)row * 64 + l * 4);
        __half2 h0 = __floats2half2_rn(v.x, v.y);
        __half2 h1 = __floats2half2_rn(v.z, v.w);
        uint2 pk = make_uint2(*(unsigned*)&h0, *(unsigned*)&h1);
        *(uint2*)(xh + (size_t)row * 64 + l * 4) = pk;
        const float4 A0 = *(const float4*)(sA + l * 4);
        const float4 A1 = *(const float4*)(sA + 64 + l * 4);
        const float4 A2 = *(const float4*)(sA + 128 + l * 4);
        const float4 A3 = *(const float4*)(sA + 192 + l * 4);
        float p0 = fmaf(v.x, A0.x, fmaf(v.y, A0.y, fmaf(v.z, A0.z, v.w * A0.w)));
        float p1 = fmaf(v.x, A1.x, fmaf(v.y, A1.y, fmaf(v.z, A1.z, v.w * A1.w)));
        float p2 = fmaf(v.x, A2.x, fmaf(v.y, A2.y, fmaf(v.z, A2.z, v.w * A2.w)));
        float p3 = fmaf(v.x, A3.x, fmaf(v.y, A3.y, fmaf(v.z, A3.z, v.w * A3.w)));
        #pragma unroll
        for (int off = 1; off < 16; off <<= 1) {
            p0 += __shfl_xor(p0, off);
            p1 += __shfl_xor(p1, off);
            p2 += __shfl_xor(p2, off);
            p3 += __shfl_xor(p3, off);
        }
        if (l == 0) {
            S[row] = p0;
            S[(size_t)n + row] = p1;
            S[2 * (size_t)n + row] = p2;
            S[3 * (size_t)n + row] = p3;
        }
    }
}

// ----------------------- per-edge weights + den ----------------------------

__global__ __launch_bounds__(1024) void wgt1_kernel(
        const int* __restrict__ esrcP, const int* __restrict__ binBaseP,
        const int* __restrict__ esrcN, const int* __restrict__ binBaseN,
        const float* __restrict__ S,
        float* __restrict__ wgtP, float* __restrict__ wgtN,
        float* __restrict__ rdenP, float* __restrict__ rdenN, int n) {
    __shared__ float dP[BIN_SPAN], dN[BIN_SPAN];
    int b = blockIdx.x, tid = threadIdx.x;
    if (tid < BIN_SPAN) { dP[tid] = 0.f; dN[tid] = 0.f; }
    __syncthreads();
    int nodeBase = b << BIN_SHIFT;
    const float* siP = S;                     const float* sjP = S + (size_t)n;
    const float* siN = S + 2 * (size_t)n;     const float* sjN = S + 3 * (size_t)n;
    for (int i = binBaseP[b] + tid, hi = binBaseP[b + 1]; i < hi; i += 1024) {
        int rec = esrcP[i];
        int src = (int)((unsigned)rec >> BIN_SHIFT);
        int dl  = rec & (BIN_SPAN - 1);
        float w = __expf(siP[nodeBase + dl] + sjP[src]);
        wgtP[i] = w;
        atomicAdd(&dP[dl], w);
    }
    for (int i = binBaseN[b] + tid, hi = binBaseN[b + 1]; i < hi; i += 1024) {
        int rec = esrcN[i];
        int src = (int)((unsigned)rec >> BIN_SHIFT);
        int dl  = rec & (BIN_SPAN - 1);
        float w = __expf(siN[nodeBase + dl] + sjN[src]);
        wgtN[i] = w;
        atomicAdd(&dN[dl], w);
    }
    __syncthreads();
    if (tid < BIN_SPAN) {
        int node = nodeBase + tid;
        if (node < n) {
            rdenP[node] = 1.0f / fmaxf(dP[tid], 1e-16f);
            rdenN[node] = 1.0f / fmaxf(dN[tid], 1e-16f);
        }
    }
}

// pos: L=bp(S0,S1) H=up(S4,S5).  neg: L=un(S6,S7) H=bn(S2,S3).
__global__ __launch_bounds__(1024) void wgt2_kernel(
        const int* __restrict__ esrcP, const int* __restrict__ binBaseP,
        const int* __restrict__ esrcN, const int* __restrict__ binBaseN,
        const float* __restrict__ S,
        unsigned* __restrict__ wgtP, unsigned* __restrict__ wgtN,
        float* __restrict__ rdenPL, float* __restrict__ rdenPH,
        float* __restrict__ rdenNL, float* __restrict__ rdenNH, int n) {
    __shared__ float dPL[BIN_SPAN], dPH[BIN_SPAN], dNL[BIN_SPAN], dNH[BIN_SPAN];
    int b = blockIdx.x, tid = threadIdx.x;
    if (tid < BIN_SPAN) { dPL[tid] = 0.f; dPH[tid] = 0.f; dNL[tid] = 0.f; dNH[tid] = 0.f; }
    __syncthreads();
    int nodeBase = b << BIN_SHIFT;
    const float* S0 = S;                   const float* S1 = S + (size_t)n;
    const float* S2 = S + 2 * (size_t)n;   const float* S3 = S + 3 * (size_t)n;
    const float* S4 = S + 4 * (size_t)n;   const float* S5 = S + 5 * (size_t)n;
    const float* S6 = S + 6 * (size_t)n;   const float* S7 = S + 7 * (size_t)n;
    for (int i = binBaseP[b] + tid, hi = binBaseP[b + 1]; i < hi; i += 1024) {
        int rec = esrcP[i];
        int src = (int)((unsigned)rec >> BIN_SHIFT);
        int dl  = rec & (BIN_SPAN - 1);
        float wL = __expf(S0[nodeBase + dl] + S1[src]);   // bp
        float wH = __expf(S4[nodeBase + dl] + S5[src]);   // up
        __half2 h = __floats2half2_rn(wL, wH);
        wgtP[i] = *(unsigned*)&h;
        atomicAdd(&dPL[dl], wL);
        atomicAdd(&dPH[dl], wH);
    }
    for (int i = binBaseN[b] + tid, hi = binBaseN[b + 1]; i < hi; i += 1024) {
        int rec = esrcN[i];
        int src = (int)((unsigned)rec >> BIN_SHIFT);
        int dl  = rec & (BIN_SPAN - 1);
        float wL = __expf(S6[nodeBase + dl] + S7[src]);   // un
        float wH = __expf(S2[nodeBase + dl] + S3[src]);   // bn
        __half2 h = __floats2half2_rn(wL, wH);
        wgtN[i] = *(unsigned*)&h;
        atomicAdd(&dNL[dl], wL);
        atomicAdd(&dNH[dl], wH);
    }
    __syncthreads();
    if (tid < BIN_SPAN) {
        int node = nodeBase + tid;
        if (node < n) {
            rdenPL[node] = 1.0f / fmaxf(dPL[tid], 1e-16f);
            rdenPH[node] = 1.0f / fmaxf(dPH[tid], 1e-16f);
            rdenNL[node] = 1.0f / fmaxf(dNL[tid], 1e-16f);
            rdenNH[node] = 1.0f / fmaxf(dNH[tid], 1e-16f);
        }
    }
}

// --------------------- layer 1 aggregation (pure gather) -------------------

// pos+neg fused (idx<n -> pos). Writes normalized fp16 row half into
// AGGH1[node][0:64] (pos/aggP) or AGGH1[node][64:128] (neg/aggN).
__global__ __launch_bounds__(256) void agg64_kernel(
        const int* __restrict__ rpA, const int* __restrict__ esA,
        const float* __restrict__ wA, const float* __restrict__ rdA,
        const int* __restrict__ rpB, const int* __restrict__ esB,
        const float* __restrict__ wB, const float* __restrict__ rdB,
        const __half* __restrict__ xh, __half* __restrict__ AGGH1, int n) {
    int w = threadIdx.x >> 6, lane = threadIdx.x & 63;
    int idx = blockIdx.x * 4 + w;
    if (idx >= 2 * n) return;
    bool second = idx >= n;
    int node = second ? idx - n : idx;
    const int*   rp = second ? rpB : rpA;
    const int*   es = second ? esB : esA;
    const float* wg = second ? wB : wA;
    float r = (second ? rdB : rdA)[node];

    int start = rp[node], len = rp[node + 1] - start;
    int g3 = lane >> 3, q8 = lane & 7;
    float a0=0,a1=0,a2=0,a3=0,a4=0,a5=0,a6=0,a7=0;

    for (int cb = 0; cb < len; cb += 64) {
        int t = cb + lane;
        float wv = 0.f; int sr = 0;
        if (t < len) { wv = wg[start + t]; sr = es[start + t]; }
        int cl = len - cb; if (cl > 64) cl = 64;
        #pragma unroll 2
        for (int u = 0; u < cl; u += 8) {
            int e = u + g3;
            float wt = __shfl(wv, e);
            int   sp = __shfl(sr, e);
            if (e < cl) {
                size_t st = (size_t)((unsigned)sp >> BIN_SHIFT);
                const uint4 pk = *(const uint4*)(xh + st * 64 + q8 * 8);
                float2 f0 = __half22float2(*(const __half2*)&pk.x);
                float2 f1 = __half22float2(*(const __half2*)&pk.y);
                float2 f2 = __half22float2(*(const __half2*)&pk.z);
                float2 f3 = __half22float2(*(const __half2*)&pk.w);
                a0 = fmaf(wt, f0.x, a0); a1 = fmaf(wt, f0.y, a1);
                a2 = fmaf(wt, f1.x, a2); a3 = fmaf(wt, f1.y, a3);
                a4 = fmaf(wt, f2.x, a4); a5 = fmaf(wt, f2.y, a5);
                a6 = fmaf(wt, f3.x, a6); a7 = fmaf(wt, f3.y, a7);
            }
        }
    }
    #pragma unroll
    for (int off = 8; off <= 32; off <<= 1) {
        a0 += __shfl_xor(a0, off); a1 += __shfl_xor(a1, off);
        a2 += __shfl_xor(a2, off); a3 += __shfl_xor(a3, off);
        a4 += __shfl_xor(a4, off); a5 += __shfl_xor(a5, off);
        a6 += __shfl_xor(a6, off); a7 += __shfl_xor(a7, off);
    }
    if (g3 == 0) {
        __half2 p0 = __floats2half2_rn(a0 * r, a1 * r);
        __half2 p1 = __floats2half2_rn(a2 * r, a3 * r);
        __half2 p2 = __floats2half2_rn(a4 * r, a5 * r);
        __half2 p3 = __floats2half2_rn(a6 * r, a7 * r);
        uint4 pk = make_uint4(*(unsigned*)&p0, *(unsigned*)&p1, *(unsigned*)&p2, *(unsigned*)&p3);
        *(uint4*)(AGGH1 + (size_t)node * 128 + (second ? 64 : 0) + q8 * 8) = pk;
    }
}

// ---------------- layer 1 MLP + tanh + layer-2 scores ----------------------

#define W1PAD 132   // halves; col stride 66 dwords, 66%32=2 -> 2-way (free)

__global__ __launch_bounds__(256) void mlp1f_kernel(
        const __half* __restrict__ AGGH1, const __half* __restrict__ xh,
        const float* __restrict__ W1b, const float* __restrict__ b1b,
        const float* __restrict__ W1u, const float* __restrict__ b1u,
        const float* __restrict__ a2b, const float* __restrict__ a2u,
        __half* __restrict__ zh, float* __restrict__ S, int n) {
    __shared__ __half sW[2][32][W1PAD];
    __shared__ float sA2[128];
    __shared__ float sB1[2][32];
    __shared__ alignas(16) float sIn[4][192];
    for (int i = threadIdx.x; i < 8192; i += 256) {
        int fam = i >> 12, r = i & 4095;
        int col = r & 31, k = r >> 5;
        sW[fam][col][k] = __float2half(fam ? W1u[r] : W1b[r]);
    }
    for (int i = threadIdx.x; i < 128; i += 256)
        sA2[i] = (i < 64) ? a2b[i] : a2u[i - 64];
    if (threadIdx.x < 64) {
        int f = threadIdx.x >> 5, c = threadIdx.x & 31;
        sB1[f][c] = f ? b1u[c] : b1b[c];
    }
    __syncthreads();

    int w = threadIdx.x >> 6, lane = threadIdx.x & 63;
    int f = lane >> 5, col = lane & 31;
    int G = (n + 3) >> 2;
    for (int grp = blockIdx.x; grp < G; grp += gridDim.x) {
        int node = grp * 4 + w;
        if (node >= n) continue;
        // stage [aggP(64)|aggN(64)|x(64)] as f32 (same-wave, no barrier)
        if (lane < 32) {
            int m = lane * 4;
            uint2 v = *(const uint2*)(AGGH1 + (size_t)node * 128 + m);
            float2 f0 = __half22float2(*(const __half2*)&v.x);
            float2 f1 = __half22float2(*(const __half2*)&v.y);
            *(float4*)(&sIn[w][m]) = make_float4(f0.x, f0.y, f1.x, f1.y);
        } else if (lane < 48) {
            int j = (lane - 32) * 4;
            uint2 v = *(const uint2*)(xh + (size_t)node * 64 + j);
            float2 f0 = __half22float2(*(const __half2*)&v.x);
            float2 f1 = __half22float2(*(const __half2*)&v.y);
            *(float4*)(&sIn[w][128 + j]) = make_float4(f0.x, f0.y, f1.x, f1.y);
        }
        // MLP: f=0 (b-family) uses aggP + x; f=1 (u-family) uses aggN + x.
        const float* inA = &sIn[w][f * 64];
        const float* inX = &sIn[w][128];
        const __half* wr = &sW[f][col][0];
        float acc = sB1[f][col];
        #pragma unroll
        for (int t = 0; t < 16; ++t) {
            float4 iv = *(const float4*)(inA + 4 * t);
            uint2 wp = *(const uint2*)(wr + 4 * t);
            float2 w0 = __half22float2(*(const __half2*)&wp.x);
            float2 w1 = __half22float2(*(const __half2*)&wp.y);
            acc = fmaf(iv.x, w0.x, fmaf(iv.y, w0.y, fmaf(iv.z, w1.x, fmaf(iv.w, w1.y, acc))));
        }
        #pragma unroll
        for (int t = 0; t < 16; ++t) {
            float4 iv = *(const float4*)(inX + 4 * t);
            uint2 wp = *(const uint2*)(wr + 64 + 4 * t);
            float2 w0 = __half22float2(*(const __half2*)&wp.x);
            float2 w1 = __half22float2(*(const __half2*)&wp.y);
            acc = fmaf(iv.x, w0.x, fmaf(iv.y, w0.y, fmaf(iv.z, w1.x, fmaf(iv.w, w1.y, acc))));
        }
        float zv = tanhf(acc);
        zh[(size_t)node * 64 + f * 32 + col] = __float2half(zv);
        // layer-2 score dots: z-half f=0 is zb, f=1 is zu.
        float p0 = zv * sA2[col];         // vs a2b[:32]
        float p1 = zv * sA2[32 + col];    // vs a2b[32:]
        float p2 = zv * sA2[64 + col];    // vs a2u[:32]
        float p3 = zv * sA2[96 + col];    // vs a2u[32:]
        #pragma unroll
        for (int off = 1; off < 32; off <<= 1) {
            p0 += __shfl_xor(p0, off);
            p1 += __shfl_xor(p1, off);
            p2 += __shfl_xor(p2, off);
            p3 += __shfl_xor(p3, off);
        }
        if (col == 0) {
            if (f == 0) {   // zb: S0=zb.a2b[:32] S1=zb.a2b[32:] S6=zb.a2u[:32] S7=zb.a2u[32:]
                S[node] = p0;
                S[(size_t)n + node] = p1;
                S[6 * (size_t)n + node] = p2;
                S[7 * (size_t)n + node] = p3;
            } else {        // zu: S2=zu.a2b[:32] S3=zu.a2b[32:] S4=zu.a2u[:32] S5=zu.a2u[32:]
                S[2 * (size_t)n + node] = p0;
                S[3 * (size_t)n + node] = p1;
                S[4 * (size_t)n + node] = p2;
                S[5 * (size_t)n + node] = p3;
            }
        }
    }
}

// ------------------- layer 2 aggregation (paired gather) -------------------

// AGGH row layout per node: [bp(32) | bn(32) | up(32) | un(32)] fp16.
__global__ __launch_bounds__(256) void agg32pair_kernel(
        const int* __restrict__ rpA, const int* __restrict__ esA,
        const unsigned* __restrict__ wA,
        const float* __restrict__ rdLA, const float* __restrict__ rdHA,
        const int* __restrict__ rpB, const int* __restrict__ esB,
        const unsigned* __restrict__ wB,
        const float* __restrict__ rdLB, const float* __restrict__ rdHB,
        const __half* __restrict__ zh, __half* __restrict__ AGGH, int n) {
    int w = threadIdx.x >> 6, lane = threadIdx.x & 63;
    int idx = blockIdx.x * 4 + w;
    if (idx >= 2 * n) return;
    bool second = idx >= n;
    int node = second ? idx - n : idx;
    const int*      rp  = second ? rpB  : rpA;
    const int*      es  = second ? esB  : esA;
    const unsigned* wg  = second ? wB   : wA;
    const float*    rdL = second ? rdLB : rdLA;
    const float*    rdH = second ? rdHB : rdHA;

    int start = rp[node], len = rp[node + 1] - start;
    int g3 = lane >> 3, q8 = lane & 7;
    bool lowf = q8 < 4;
    float a0=0,a1=0,a2=0,a3=0,a4=0,a5=0,a6=0,a7=0;

    for (int cb = 0; cb < len; cb += 64) {
        int t = cb + lane;
        unsigned wv = 0; int sr = 0;
        if (t < len) { wv = wg[start + t]; sr = es[start + t]; }
        int cl = len - cb; if (cl > 64) cl = 64;
        #pragma unroll 2
        for (int u = 0; u < cl; u += 8) {
            int e = u + g3;
            unsigned wp = (unsigned)__shfl((int)wv, e);
            int      sp = __shfl(sr, e);
            if (e < cl) {
                float2 wf = __half22float2(*(const __half2*)&wp);
                float wt = lowf ? wf.x : wf.y;
                size_t st = (size_t)((unsigned)sp >> BIN_SHIFT);
                const uint4 pk = *(const uint4*)(zh + st * 64 + q8 * 8);
                float2 f0 = __half22float2(*(const __half2*)&pk.x);
                float2 f1 = __half22float2(*(const __half2*)&pk.y);
                float2 f2 = __half22float2(*(const __half2*)&pk.z);
                float2 f3 = __half22float2(*(const __half2*)&pk.w);
                a0 = fmaf(wt, f0.x, a0); a1 = fmaf(wt, f0.y, a1);
                a2 = fmaf(wt, f1.x, a2); a3 = fmaf(wt, f1.y, a3);
                a4 = fmaf(wt, f2.x, a4); a5 = fmaf(wt, f2.y, a5);
                a6 = fmaf(wt, f3.x, a6); a7 = fmaf(wt, f3.y, a7);
            }
        }
    }
    #pragma unroll
    for (int off = 8; off <= 32; off <<= 1) {
        a0 += __shfl_xor(a0, off); a1 += __shfl_xor(a1, off);
        a2 += __shfl_xor(a2, off); a3 += __shfl_xor(a3, off);
        a4 += __shfl_xor(a4, off); a5 += __shfl_xor(a5, off);
        a6 += __shfl_xor(a6, off); a7 += __shfl_xor(a7, off);
    }
    if (g3 == 0) {
        float r = lowf ? rdL[node] : rdH[node];
        __half2 p0 = __floats2half2_rn(a0 * r, a1 * r);
        __half2 p1 = __floats2half2_rn(a2 * r, a3 * r);
        __half2 p2 = __floats2half2_rn(a4 * r, a5 * r);
        __half2 p3 = __floats2half2_rn(a6 * r, a7 * r);
        uint4 pk = make_uint4(*(unsigned*)&p0, *(unsigned*)&p1, *(unsigned*)&p2, *(unsigned*)&p3);
        // pos: L=bp->0, H=up->64 ; neg: L=un->96, H=bn->32
        int base = second ? (lowf ? 96 : 32) : (lowf ? 0 : 64);
        *(uint4*)(AGGH + (size_t)node * 128 + base + (q8 & 3) * 8) = pk;
    }
}

// ------------------------------- MLP 2 -------------------------------------

#define W2PAD 108   // halves; col stride 54 dwords -> ~2-way banks

__global__ __launch_bounds__(256) void mlp2_kernel(
        const __half* __restrict__ AGGH, const __half* __restrict__ zh,
        const float* __restrict__ W2b, const float* __restrict__ b2b,
        const float* __restrict__ W2u, const float* __restrict__ b2u,
        float* __restrict__ out, int n) {
    __shared__ __half sW[2][32][W2PAD];
    __shared__ float sB[2][32];
    __shared__ alignas(16) float sIn[4][2][96];
    for (int i = threadIdx.x; i < 6144; i += 256) {
        int fam = (i >= 3072), r = fam ? i - 3072 : i;
        int col = r & 31, k = r >> 5;
        sW[fam][col][k] = __float2half(fam ? W2u[r] : W2b[r]);
    }
    if (threadIdx.x < 64) {
        int f = threadIdx.x >> 5, c = threadIdx.x & 31;
        sB[f][c] = f ? b2u[c] : b2b[c];
    }
    __syncthreads();

    int w = threadIdx.x >> 6, lane = threadIdx.x & 63;
    int f = lane >> 5, col = lane & 31;
    int G = (n + 3) >> 2;
    for (int grp = blockIdx.x; grp < G; grp += gridDim.x) {
        int node = grp * 4 + w;
        if (node >= n) continue;
        // stage [bp|bn|zb] and [up|un|zu] as f32 (same-wave, no barrier)
        if (lane < 32) {
            int m = lane * 4;                      // 0..124 within AGGH row
            uint2 v = *(const uint2*)(AGGH + (size_t)node * 128 + m);
            float2 f0 = __half22float2(*(const __half2*)&v.x);
            float2 f1 = __half22float2(*(const __half2*)&v.y);
            float* dp = &sIn[w][m >> 6][m & 63];
            *(float4*)dp = make_float4(f0.x, f0.y, f1.x, f1.y);
        } else {
            int j = (lane - 32) * 2;               // 0..62 within zh row
            unsigned v = *(const unsigned*)(zh + (size_t)node * 64 + j);
            float2 fz = __half22float2(*(const __half2*)&v);
            float* dp = &sIn[w][j >> 5][64 + (j & 31)];
            dp[0] = fz.x; dp[1] = fz.y;
        }
        const float* in = sIn[w][f];
        const __half* wr = &sW[f][col][0];
        float acc = sB[f][col];
        #pragma unroll
        for (int t = 0; t < 24; ++t) {
            float4 iv = *(const float4*)(in + 4 * t);
            uint2 wp = *(const uint2*)(wr + 4 * t);
            float2 w0 = __half22float2(*(const __half2*)&wp.x);
            float2 w1 = __half22float2(*(const __half2*)&wp.y);
            acc = fmaf(iv.x, w0.x, fmaf(iv.y, w0.y, fmaf(iv.z, w1.x, fmaf(iv.w, w1.y, acc))));
        }
        out[(size_t)node * 64 + f * 32 + col] = tanhf(acc);
    }
}

// ------------------------------ launcher -----------------------------------

extern "C" void kernel_launch(void* const* d_in, const int* in_sizes, int n_in,
                              void* d_out, int out_size, void* d_ws, size_t ws_size,
                              hipStream_t stream) {
    const float* x   = (const float*)d_in[0];
    const int*   pos = (const int*)d_in[1];
    const int*   neg = (const int*)d_in[2];
    const float* a1b = (const float*)d_in[3];
    const float* a1u = (const float*)d_in[4];
    const float* W1b = (const float*)d_in[5];
    const float* b1b = (const float*)d_in[6];
    const float* W1u = (const float*)d_in[7];
    const float* b1u = (const float*)d_in[8];
    const float* a2b = (const float*)d_in[9];
    const float* a2u = (const float*)d_in[10];
    const float* W2b = (const float*)d_in[11];
    const float* b2b = (const float*)d_in[12];
    const float* W2u = (const float*)d_in[13];
    const float* b2u = (const float*)d_in[14];
    float* out = (float*)d_out;

    const int n  = in_sizes[0] / 64;
    const int Ep = in_sizes[1] / 2;
    const int En = in_sizes[2] / 2;
    const int* ps = pos;  const int* pd = pos + Ep;
    const int* ns = neg;  const int* nd = neg + En;
    const int nbin = (n + BIN_SPAN - 1) >> BIN_SHIFT;

    // ws layout (4-byte words)
    unsigned* W = (unsigned*)d_ws;
    size_t o = 0;
    float* S        = (float*)(W + o); o += 8 * (size_t)n;
    int*   rowptrP  = (int*)(W + o);   o += n + 1;
    int*   rowptrN  = (int*)(W + o);   o += n + 1;
    int*   binCntP  = (int*)(W + o);   o += nbin;
    int*   binCntN  = (int*)(W + o);   o += nbin;
    int*   binBaseP = (int*)(W + o);   o += nbin + 1;
    int*   binBaseN = (int*)(W + o);   o += nbin + 1;
    int*   gCur     = (int*)(W + o);   o += nbin;
    int*   esrcP    = (int*)(W + o);   o += Ep;
    int*   esrcN    = (int*)(W + o);   o += En;
    float* RDEN     = (float*)(W + o); o += 4 * (size_t)n;
    o = (o + 3) & ~(size_t)3;
    __half* XH      = (__half*)(W + o); o += 32 * (size_t)n;   // x rows fp16
    __half* ZH      = (__half*)(W + o); o += 32 * (size_t)n;   // z rows fp16
    float* WGT      = (float*)(W + o);  o += (size_t)Ep + En;
    o = (o + 3) & ~(size_t)3;
    __half* AGGH    = (__half*)(W + o); o += 64 * (size_t)n;   // [n][128] fp16
    int*   binned   = (int*)AGGH;   // CSR-build scratch aliases AGGH/AGGH1
    __half* AGGH1   = AGGH;         // layer-1 agg rows [aggP|aggN], consumed
                                    // by mlp1f before agg32pair overwrites

    const int B = 256;
    const int aggBlocks = (2 * n + 3) / 4;
    auto gcap = [](long t, int b) { long g = (t + b - 1) / b; return (int)(g < 2048 ? g : 2048); };

    // ---------------- CSR build ----------------
    hipMemsetAsync(binCntP, 0, (size_t)nbin * sizeof(int), stream);
    hipMemsetAsync(binCntN, 0, (size_t)nbin * sizeof(int), stream);
    bin_hist_kernel<<<gcap(Ep, B), B, 0, stream>>>(pd, Ep, binCntP, nbin);
    bin_hist_kernel<<<gcap(En, B), B, 0, stream>>>(nd, En, binCntN, nbin);

    scan_bins_kernel<<<1, 256, 0, stream>>>(binCntP, nbin, binBaseP, gCur, rowptrP, n, Ep);
    bin_scatter_kernel<<<(Ep + 4095) / 4096, 256, 0, stream>>>(ps, pd, Ep, binBaseP, gCur, binned, nbin);
    bin_finalize_kernel<<<nbin, 256, 0, stream>>>(binned, binBaseP, rowptrP, esrcP, n);

    scan_bins_kernel<<<1, 256, 0, stream>>>(binCntN, nbin, binBaseN, gCur, rowptrN, n, En);
    bin_scatter_kernel<<<(En + 4095) / 4096, 256, 0, stream>>>(ns, nd, En, binBaseN, gCur, binned, nbin);
    bin_finalize_kernel<<<nbin, 256, 0, stream>>>(binned, binBaseN, rowptrN, esrcN, n);

    // ---------------- Layer 1 ----------------
    scalars1_kernel<<<512, B, 0, stream>>>(x, a1b, a1u, S, XH, n);
    wgt1_kernel<<<nbin, 1024, 0, stream>>>(esrcP, binBaseP, esrcN, binBaseN, S,
                                           WGT, WGT + Ep, RDEN, RDEN + n, n);
    agg64_kernel<<<aggBlocks, 256, 0, stream>>>(
        rowptrP, esrcP, WGT,      RDEN,
        rowptrN, esrcN, WGT + Ep, RDEN + n,
        XH, AGGH1, n);
    mlp1f_kernel<<<4096, B, 0, stream>>>(AGGH1, XH, W1b, b1b, W1u, b1u,
                                         a2b, a2u, ZH, S, n);

    // ---------------- Layer 2 ----------------
    wgt2_kernel<<<nbin, 1024, 0, stream>>>(esrcP, binBaseP, esrcN, binBaseN, S,
                                           (unsigned*)WGT, (unsigned*)WGT + Ep,
                                           RDEN, RDEN + n, RDEN + 2 * (size_t)n, RDEN + 3 * (size_t)n, n);
    agg32pair_kernel<<<aggBlocks, 256, 0, stream>>>(
        rowptrP, esrcP, (unsigned*)WGT,      RDEN,                 RDEN + n,
        rowptrN, esrcN, (unsigned*)WGT + Ep, RDEN + 2 * (size_t)n, RDEN + 3 * (size_t)n,
        ZH, AGGH, n);
    mlp2_kernel<<<4096, B, 0, stream>>>(AGGH, ZH, W2b, b2b, W2u, b2u, out, n);
}

// Round 9
// 458.889 us; speedup vs baseline: 1.2848x; 1.1937x over previous
//
#include <hip/hip_runtime.h>
#include <hip/hip_fp16.h>
#include <math.h>

// ---------------------------------------------------------------------------
// SNEA pipeline (MFMA MLPs, fp16 data paths):
//   CSR build: binned counting sort (bin = dst>>9), packed recs src<<9|dstLocal.
//   scalars1: layer-1 score projections + fp16 copy of x (XH).
//   wgt1/wgt2: per-edge softmax weights + rden per node (LDS per bin).
//   agg64:    pure gather (8 edges in flight, fp16 rows, f32 accum) ->
//             normalized fp16 AGGH1[n][128] = [aggP|aggN].
//   pack_weights: one-time repack of W1/W2/alpha2 into MFMA B-fragment order.
//   mlp1f:    MFMA 16x16x32_f16: [16 nodes x 128] @ [128x32] per family ->
//             tanh -> ZH fp16 (via per-wave LDS tile) + layer-2 score dots
//             as one extra MFMA (z[16x32] @ a2[32x4]).
//   agg32pair: paired gather over ZH -> fp16 AGGH[n][128] (bp|bn|up|un).
//   mlp2:     MFMA [16 x 96] @ [96x32] per family -> tanh -> out (f32).
// No segment-max anywhere: scores ~N(0,1), unstabilized exp is f32-safe and
// mathematically identical to the max-subtracted softmax.
// MFMA layouts (gfx950, verified per guide m89/m91): A: row=lane&15,
// k=(lane>>4)*8+j (contiguous); B: col=lane&15, same k; C/D: col=lane&15,
// row=(lane>>4)*4+reg.
// ---------------------------------------------------------------------------

#define BIN_SHIFT 9
#define BIN_SPAN  512
#define NBIN_MAX  256          // n <= 131072; src fits 23 bits

typedef _Float16 half8 __attribute__((ext_vector_type(8)));
typedef float f32x4 __attribute__((ext_vector_type(4)));

// ----------------------------- CSR build ----------------------------------

__global__ __launch_bounds__(256) void bin_hist_kernel(const int* __restrict__ dst, int E,
                                                       int* __restrict__ binCnt, int nbin) {
    __shared__ int lc[NBIN_MAX];
    if (threadIdx.x < NBIN_MAX) lc[threadIdx.x] = 0;
    __syncthreads();
    int i = blockIdx.x * blockDim.x + threadIdx.x;
    int stride = gridDim.x * blockDim.x;
    for (; i < E; i += stride) atomicAdd(&lc[dst[i] >> BIN_SHIFT], 1);
    __syncthreads();
    if (threadIdx.x < nbin && lc[threadIdx.x]) atomicAdd(&binCnt[threadIdx.x], lc[threadIdx.x]);
}

__global__ __launch_bounds__(256) void scan_bins_kernel(const int* __restrict__ binCnt, int nbin,
                                                        int* __restrict__ binBase,
                                                        int* __restrict__ gCursor,
                                                        int* __restrict__ rowptr, int n, int E) {
    __shared__ int sd[256];
    int tid = threadIdx.x;
    int v = (tid < nbin) ? binCnt[tid] : 0;
    sd[tid] = v; __syncthreads();
    for (int off = 1; off < 256; off <<= 1) {
        int t = (tid >= off) ? sd[tid - off] : 0;
        __syncthreads();
        sd[tid] += t;
        __syncthreads();
    }
    if (tid < nbin) { binBase[tid] = sd[tid] - v; gCursor[tid] = 0; }
    if (tid == nbin - 1) binBase[nbin] = sd[tid];
    if (tid == 0) rowptr[n] = E;
}

__global__ __launch_bounds__(256) void bin_scatter_kernel(
        const int* __restrict__ src, const int* __restrict__ dst, int E,
        const int* __restrict__ binBase, int* __restrict__ gCursor,
        int* __restrict__ binned, int nbin) {
    __shared__ int lc[NBIN_MAX];
    __shared__ int lbase[NBIN_MAX];
    if (threadIdx.x < NBIN_MAX) lc[threadIdx.x] = 0;
    __syncthreads();
    int base0 = blockIdx.x * 4096 + threadIdx.x * 16;
    int rank[16], bn[16];
    #pragma unroll
    for (int k = 0; k < 16; ++k) {
        int i = base0 + k;
        if (i < E) {
            int b = dst[i] >> BIN_SHIFT;
            bn[k] = b;
            rank[k] = atomicAdd(&lc[b], 1);
        }
    }
    __syncthreads();
    if (threadIdx.x < nbin && lc[threadIdx.x])
        lbase[threadIdx.x] = atomicAdd(&gCursor[threadIdx.x], lc[threadIdx.x]);
    __syncthreads();
    #pragma unroll
    for (int k = 0; k < 16; ++k) {
        int i = base0 + k;
        if (i < E) {
            int b = bn[k];
            int pos = binBase[b] + lbase[b] + rank[k];
            binned[pos] = (src[i] << BIN_SHIFT) | (dst[i] & (BIN_SPAN - 1));
        }
    }
}

__global__ __launch_bounds__(256) void bin_finalize_kernel(
        const int* __restrict__ binned, const int* __restrict__ binBase,
        int* __restrict__ rowptr, int* __restrict__ esrc, int n) {
    __shared__ int hist[BIN_SPAN];
    __shared__ int curs[BIN_SPAN];
    __shared__ int psum[256];
    int b = blockIdx.x, tid = threadIdx.x;
    int lo = binBase[b], hi = binBase[b + 1];
    int nodeBase = b << BIN_SHIFT;
    hist[tid] = 0; hist[tid + 256] = 0;
    __syncthreads();
    for (int i = lo + tid; i < hi; i += 256)
        atomicAdd(&hist[binned[i] & (BIN_SPAN - 1)], 1);
    __syncthreads();
    int a0 = hist[2 * tid], a1 = hist[2 * tid + 1];
    int ps = a0 + a1;
    psum[tid] = ps; __syncthreads();
    for (int off = 1; off < 256; off <<= 1) {
        int t = (tid >= off) ? psum[tid - off] : 0;
        __syncthreads();
        psum[tid] += t;
        __syncthreads();
    }
    int excl = psum[tid] - ps;
    curs[2 * tid] = excl;
    curs[2 * tid + 1] = excl + a0;
    {
        int idx0 = nodeBase + 2 * tid;
        if (idx0 <= n)     rowptr[idx0]     = lo + excl;
        if (idx0 + 1 <= n) rowptr[idx0 + 1] = lo + excl + a0;
    }
    __syncthreads();
    for (int i = lo + tid; i < hi; i += 256) {
        int rec = binned[i];
        int slot = lo + atomicAdd(&curs[rec & (BIN_SPAN - 1)], 1);
        esrc[slot] = rec;      // keep packed
    }
}

// --------------------------- scalars (layer 1) ------------------------------

__global__ __launch_bounds__(256) void scalars1_kernel(
        const float* __restrict__ x,
        const float* __restrict__ a1b, const float* __restrict__ a1u,
        float* __restrict__ S, __half* __restrict__ xh, int n) {
    __shared__ float sA[256];
    for (int k = threadIdx.x; k < 256; k += blockDim.x)
        sA[k] = (k < 128) ? a1b[k] : a1u[k - 128];
    __syncthreads();
    int grp = threadIdx.x >> 4, l = threadIdx.x & 15;
    for (int row = blockIdx.x * 16 + grp; row < n; row += gridDim.x * 16) {
        const float4 v = *(const float4*)(x + (size_t)row * 64 + l * 4);
        __half2 h0 = __floats2half2_rn(v.x, v.y);
        __half2 h1 = __floats2half2_rn(v.z, v.w);
        uint2 pk = make_uint2(*(unsigned*)&h0, *(unsigned*)&h1);
        *(uint2*)(xh + (size_t)row * 64 + l * 4) = pk;
        const float4 A0 = *(const float4*)(sA + l * 4);
        const float4 A1 = *(const float4*)(sA + 64 + l * 4);
        const float4 A2 = *(const float4*)(sA + 128 + l * 4);
        const float4 A3 = *(const float4*)(sA + 192 + l * 4);
        float p0 = fmaf(v.x, A0.x, fmaf(v.y, A0.y, fmaf(v.z, A0.z, v.w * A0.w)));
        float p1 = fmaf(v.x, A1.x, fmaf(v.y, A1.y, fmaf(v.z, A1.z, v.w * A1.w)));
        float p2 = fmaf(v.x, A2.x, fmaf(v.y, A2.y, fmaf(v.z, A2.z, v.w * A2.w)));
        float p3 = fmaf(v.x, A3.x, fmaf(v.y, A3.y, fmaf(v.z, A3.z, v.w * A3.w)));
        #pragma unroll
        for (int off = 1; off < 16; off <<= 1) {
            p0 += __shfl_xor(p0, off);
            p1 += __shfl_xor(p1, off);
            p2 += __shfl_xor(p2, off);
            p3 += __shfl_xor(p3, off);
        }
        if (l == 0) {
            S[row] = p0;
            S[(size_t)n + row] = p1;
            S[2 * (size_t)n + row] = p2;
            S[3 * (size_t)n + row] = p3;
        }
    }
}

// ----------------------- per-edge weights + den ----------------------------

__global__ __launch_bounds__(1024) void wgt1_kernel(
        const int* __restrict__ esrcP, const int* __restrict__ binBaseP,
        const int* __restrict__ esrcN, const int* __restrict__ binBaseN,
        const float* __restrict__ S,
        float* __restrict__ wgtP, float* __restrict__ wgtN,
        float* __restrict__ rdenP, float* __restrict__ rdenN, int n) {
    __shared__ float dP[BIN_SPAN], dN[BIN_SPAN];
    int b = blockIdx.x, tid = threadIdx.x;
    if (tid < BIN_SPAN) { dP[tid] = 0.f; dN[tid] = 0.f; }
    __syncthreads();
    int nodeBase = b << BIN_SHIFT;
    const float* siP = S;                     const float* sjP = S + (size_t)n;
    const float* siN = S + 2 * (size_t)n;     const float* sjN = S + 3 * (size_t)n;
    for (int i = binBaseP[b] + tid, hi = binBaseP[b + 1]; i < hi; i += 1024) {
        int rec = esrcP[i];
        int src = (int)((unsigned)rec >> BIN_SHIFT);
        int dl  = rec & (BIN_SPAN - 1);
        float w = __expf(siP[nodeBase + dl] + sjP[src]);
        wgtP[i] = w;
        atomicAdd(&dP[dl], w);
    }
    for (int i = binBaseN[b] + tid, hi = binBaseN[b + 1]; i < hi; i += 1024) {
        int rec = esrcN[i];
        int src = (int)((unsigned)rec >> BIN_SHIFT);
        int dl  = rec & (BIN_SPAN - 1);
        float w = __expf(siN[nodeBase + dl] + sjN[src]);
        wgtN[i] = w;
        atomicAdd(&dN[dl], w);
    }
    __syncthreads();
    if (tid < BIN_SPAN) {
        int node = nodeBase + tid;
        if (node < n) {
            rdenP[node] = 1.0f / fmaxf(dP[tid], 1e-16f);
            rdenN[node] = 1.0f / fmaxf(dN[tid], 1e-16f);
        }
    }
}

// pos: L=bp(S0,S1) H=up(S4,S5).  neg: L=un(S6,S7) H=bn(S2,S3).
__global__ __launch_bounds__(1024) void wgt2_kernel(
        const int* __restrict__ esrcP, const int* __restrict__ binBaseP,
        const int* __restrict__ esrcN, const int* __restrict__ binBaseN,
        const float* __restrict__ S,
        unsigned* __restrict__ wgtP, unsigned* __restrict__ wgtN,
        float* __restrict__ rdenPL, float* __restrict__ rdenPH,
        float* __restrict__ rdenNL, float* __restrict__ rdenNH, int n) {
    __shared__ float dPL[BIN_SPAN], dPH[BIN_SPAN], dNL[BIN_SPAN], dNH[BIN_SPAN];
    int b = blockIdx.x, tid = threadIdx.x;
    if (tid < BIN_SPAN) { dPL[tid] = 0.f; dPH[tid] = 0.f; dNL[tid] = 0.f; dNH[tid] = 0.f; }
    __syncthreads();
    int nodeBase = b << BIN_SHIFT;
    const float* S0 = S;                   const float* S1 = S + (size_t)n;
    const float* S2 = S + 2 * (size_t)n;   const float* S3 = S + 3 * (size_t)n;
    const float* S4 = S + 4 * (size_t)n;   const float* S5 = S + 5 * (size_t)n;
    const float* S6 = S + 6 * (size_t)n;   const float* S7 = S + 7 * (size_t)n;
    for (int i = binBaseP[b] + tid, hi = binBaseP[b + 1]; i < hi; i += 1024) {
        int rec = esrcP[i];
        int src = (int)((unsigned)rec >> BIN_SHIFT);
        int dl  = rec & (BIN_SPAN - 1);
        float wL = __expf(S0[nodeBase + dl] + S1[src]);   // bp
        float wH = __expf(S4[nodeBase + dl] + S5[src]);   // up
        __half2 h = __floats2half2_rn(wL, wH);
        wgtP[i] = *(unsigned*)&h;
        atomicAdd(&dPL[dl], wL);
        atomicAdd(&dPH[dl], wH);
    }
    for (int i = binBaseN[b] + tid, hi = binBaseN[b + 1]; i < hi; i += 1024) {
        int rec = esrcN[i];
        int src = (int)((unsigned)rec >> BIN_SHIFT);
        int dl  = rec & (BIN_SPAN - 1);
        float wL = __expf(S6[nodeBase + dl] + S7[src]);   // un
        float wH = __expf(S2[nodeBase + dl] + S3[src]);   // bn
        __half2 h = __floats2half2_rn(wL, wH);
        wgtN[i] = *(unsigned*)&h;
        atomicAdd(&dNL[dl], wL);
        atomicAdd(&dNH[dl], wH);
    }
    __syncthreads();
    if (tid < BIN_SPAN) {
        int node = nodeBase + tid;
        if (node < n) {
            rdenPL[node] = 1.0f / fmaxf(dPL[tid], 1e-16f);
            rdenPH[node] = 1.0f / fmaxf(dPH[tid], 1e-16f);
            rdenNL[node] = 1.0f / fmaxf(dNL[tid], 1e-16f);
            rdenNH[node] = 1.0f / fmaxf(dNH[tid], 1e-16f);
        }
    }
}

// --------------------- layer 1 aggregation (pure gather) -------------------

__global__ __launch_bounds__(256) void agg64_kernel(
        const int* __restrict__ rpA, const int* __restrict__ esA,
        const float* __restrict__ wA, const float* __restrict__ rdA,
        const int* __restrict__ rpB, const int* __restrict__ esB,
        const float* __restrict__ wB, const float* __restrict__ rdB,
        const __half* __restrict__ xh, __half* __restrict__ AGGH1, int n) {
    int w = threadIdx.x >> 6, lane = threadIdx.x & 63;
    int idx = blockIdx.x * 4 + w;
    if (idx >= 2 * n) return;
    bool second = idx >= n;
    int node = second ? idx - n : idx;
    const int*   rp = second ? rpB : rpA;
    const int*   es = second ? esB : esA;
    const float* wg = second ? wB : wA;
    float r = (second ? rdB : rdA)[node];

    int start = rp[node], len = rp[node + 1] - start;
    int g3 = lane >> 3, q8 = lane & 7;
    float a0=0,a1=0,a2=0,a3=0,a4=0,a5=0,a6=0,a7=0;

    for (int cb = 0; cb < len; cb += 64) {
        int t = cb + lane;
        float wv = 0.f; int sr = 0;
        if (t < len) { wv = wg[start + t]; sr = es[start + t]; }
        int cl = len - cb; if (cl > 64) cl = 64;
        #pragma unroll 2
        for (int u = 0; u < cl; u += 8) {
            int e = u + g3;
            float wt = __shfl(wv, e);
            int   sp = __shfl(sr, e);
            if (e < cl) {
                size_t st = (size_t)((unsigned)sp >> BIN_SHIFT);
                const uint4 pk = *(const uint4*)(xh + st * 64 + q8 * 8);
                float2 f0 = __half22float2(*(const __half2*)&pk.x);
                float2 f1 = __half22float2(*(const __half2*)&pk.y);
                float2 f2 = __half22float2(*(const __half2*)&pk.z);
                float2 f3 = __half22float2(*(const __half2*)&pk.w);
                a0 = fmaf(wt, f0.x, a0); a1 = fmaf(wt, f0.y, a1);
                a2 = fmaf(wt, f1.x, a2); a3 = fmaf(wt, f1.y, a3);
                a4 = fmaf(wt, f2.x, a4); a5 = fmaf(wt, f2.y, a5);
                a6 = fmaf(wt, f3.x, a6); a7 = fmaf(wt, f3.y, a7);
            }
        }
    }
    #pragma unroll
    for (int off = 8; off <= 32; off <<= 1) {
        a0 += __shfl_xor(a0, off); a1 += __shfl_xor(a1, off);
        a2 += __shfl_xor(a2, off); a3 += __shfl_xor(a3, off);
        a4 += __shfl_xor(a4, off); a5 += __shfl_xor(a5, off);
        a6 += __shfl_xor(a6, off); a7 += __shfl_xor(a7, off);
    }
    if (g3 == 0) {
        __half2 p0 = __floats2half2_rn(a0 * r, a1 * r);
        __half2 p1 = __floats2half2_rn(a2 * r, a3 * r);
        __half2 p2 = __floats2half2_rn(a4 * r, a5 * r);
        __half2 p3 = __floats2half2_rn(a6 * r, a7 * r);
        uint4 pk = make_uint4(*(unsigned*)&p0, *(unsigned*)&p1, *(unsigned*)&p2, *(unsigned*)&p3);
        *(uint4*)(AGGH1 + (size_t)node * 128 + (second ? 64 : 0) + q8 * 8) = pk;
    }
}

// --------------------- weight packing for MFMA MLPs ------------------------

// WPK1: fam(2) x kk(4) x ct(2) x lane(64) x j(8)    (W1, K=128 -> 4 K-steps)
// WPK2: fam(2) x kk(3) x ct(2) x lane(64) x j(8)    (W2, K=96  -> 3 K-steps)
// A2PK: lane(64) x j(8): B-frag for score MFMA, cols q<4 = a2 slices.
__global__ __launch_bounds__(256) void pack_weights_kernel(
        const float* __restrict__ W1b, const float* __restrict__ W1u,
        const float* __restrict__ W2b, const float* __restrict__ W2u,
        const float* __restrict__ a2b, const float* __restrict__ a2u,
        __half* __restrict__ WPK1, __half* __restrict__ WPK2,
        __half* __restrict__ A2PK) {
    int t = threadIdx.x;
    for (int i = t; i < 8192; i += 256) {
        int j = i & 7, lane = (i >> 3) & 63, ct = (i >> 9) & 1, kk = (i >> 10) & 3, fam = i >> 12;
        const float* Wx = fam ? W1u : W1b;
        int k = kk * 32 + ((lane >> 4) << 3) + j;
        int col = ct * 16 + (lane & 15);
        WPK1[i] = __float2half(Wx[k * 32 + col]);
    }
    for (int i = t; i < 6144; i += 256) {
        int j = i & 7, lane = (i >> 3) & 63, ct = (i >> 9) & 1;
        int rest = i >> 10;                 // (fam*3 + kk)
        int kk = rest % 3, fam = rest / 3;
        const float* Wx = fam ? W2u : W2b;
        int k = kk * 32 + ((lane >> 4) << 3) + j;
        int col = ct * 16 + (lane & 15);
        WPK2[i] = __float2half(Wx[k * 32 + col]);
    }
    for (int i = t; i < 512; i += 256) {
        int j = i & 7, lane = i >> 3;
        int q = lane & 15, k = ((lane >> 4) << 3) + j;
        float v = 0.f;
        if (q == 0) v = a2b[k];
        else if (q == 1) v = a2b[32 + k];
        else if (q == 2) v = a2u[k];
        else if (q == 3) v = a2u[32 + k];
        A2PK[i] = __float2half(v);
    }
}

// ---------------- layer 1 MLP (MFMA) + tanh + layer-2 scores ---------------

#define ZPITCH 40   // halves; 80B rows keep uint4/half8 accesses 16B-aligned

__global__ __launch_bounds__(256) void mlp1f_kernel(
        const __half* __restrict__ AGGH1, const __half* __restrict__ xh,
        const __half* __restrict__ WPK1, const __half* __restrict__ A2PK,
        const float* __restrict__ b1b, const float* __restrict__ b1u,
        __half* __restrict__ zh, float* __restrict__ S, int n, int ngrp) {
    __shared__ __half zLds[4][16][ZPITCH];
    int w = threadIdx.x >> 6, lane = threadIdx.x & 63;
    int fam = w & 1, l15 = lane & 15, lq = lane >> 4;

    half8 bfrag[4][2];
    #pragma unroll
    for (int kk = 0; kk < 4; ++kk)
        #pragma unroll
        for (int ct = 0; ct < 2; ++ct)
            bfrag[kk][ct] = *(const half8*)(WPK1 + (((fam * 4 + kk) * 2 + ct) << 9) + lane * 8);
    half8 a2frag = *(const half8*)(A2PK + lane * 8);
    const float* bb = fam ? b1u : b1b;
    float bias0 = bb[l15], bias1 = bb[16 + l15];

    int grp = blockIdx.x * 2 + (w >> 1);
    if (grp >= ngrp) return;
    int gbase = grp * 16;
    int arow = gbase + l15; if (arow >= n) arow = n - 1;
    const __half* aggRow = AGGH1 + (size_t)arow * 128 + fam * 64;
    const __half* xRow   = xh   + (size_t)arow * 64;

    f32x4 acc0 = {0.f, 0.f, 0.f, 0.f}, acc1 = {0.f, 0.f, 0.f, 0.f};
    #pragma unroll
    for (int kk = 0; kk < 2; ++kk) {
        half8 a = *(const half8*)(aggRow + kk * 32 + lq * 8);
        acc0 = __builtin_amdgcn_mfma_f32_16x16x32_f16(a, bfrag[kk][0], acc0, 0, 0, 0);
        acc1 = __builtin_amdgcn_mfma_f32_16x16x32_f16(a, bfrag[kk][1], acc1, 0, 0, 0);
    }
    #pragma unroll
    for (int kk = 2; kk < 4; ++kk) {
        half8 a = *(const half8*)(xRow + (kk - 2) * 32 + lq * 8);
        acc0 = __builtin_amdgcn_mfma_f32_16x16x32_f16(a, bfrag[kk][0], acc0, 0, 0, 0);
        acc1 = __builtin_amdgcn_mfma_f32_16x16x32_f16(a, bfrag[kk][1], acc1, 0, 0, 0);
    }
    // tanh + stage z tile [16][32] into this wave's LDS slot
    #pragma unroll
    for (int r = 0; r < 4; ++r) {
        int row = lq * 4 + r;
        zLds[w][row][l15]      = __float2half(tanhf(acc0[r] + bias0));
        zLds[w][row][16 + l15] = __float2half(tanhf(acc1[r] + bias1));
    }
    // coalesced ZH write: node = lane>>2, chunk = lane&3 (8 halves each)
    {
        int node = lane >> 2, chunk = lane & 3;
        uint4 v = *(const uint4*)(&zLds[w][node][chunk * 8]);
        int gn = gbase + node;
        if (gn < n) *(uint4*)(zh + (size_t)gn * 64 + fam * 32 + chunk * 8) = v;
    }
    // layer-2 score dots: z[16x32] @ a2[32x4] via one MFMA
    {
        half8 a = *(const half8*)(&zLds[w][l15][lq * 8]);
        f32x4 sacc = {0.f, 0.f, 0.f, 0.f};
        sacc = __builtin_amdgcn_mfma_f32_16x16x32_f16(a, a2frag, sacc, 0, 0, 0);
        if (l15 < 4) {
            const int mapB[4] = {0, 1, 6, 7};   // zb: S0,S1,S6,S7
            const int mapU[4] = {2, 3, 4, 5};   // zu: S2,S3,S4,S5
            int st = fam ? mapU[l15] : mapB[l15];
            #pragma unroll
            for (int r = 0; r < 4; ++r) {
                int node = gbase + lq * 4 + r;
                if (node < n) S[(size_t)st * n + node] = sacc[r];
            }
        }
    }
}

// ------------------- layer 2 aggregation (paired gather) -------------------

// AGGH row layout per node: [bp(32) | bn(32) | up(32) | un(32)] fp16.
__global__ __launch_bounds__(256) void agg32pair_kernel(
        const int* __restrict__ rpA, const int* __restrict__ esA,
        const unsigned* __restrict__ wA,
        const float* __restrict__ rdLA, const float* __restrict__ rdHA,
        const int* __restrict__ rpB, const int* __restrict__ esB,
        const unsigned* __restrict__ wB,
        const float* __restrict__ rdLB, const float* __restrict__ rdHB,
        const __half* __restrict__ zh, __half* __restrict__ AGGH, int n) {
    int w = threadIdx.x >> 6, lane = threadIdx.x & 63;
    int idx = blockIdx.x * 4 + w;
    if (idx >= 2 * n) return;
    bool second = idx >= n;
    int node = second ? idx - n : idx;
    const int*      rp  = second ? rpB  : rpA;
    const int*      es  = second ? esB  : esA;
    const unsigned* wg  = second ? wB   : wA;
    const float*    rdL = second ? rdLB : rdLA;
    const float*    rdH = second ? rdHB : rdHA;

    int start = rp[node], len = rp[node + 1] - start;
    int g3 = lane >> 3, q8 = lane & 7;
    bool lowf = q8 < 4;
    float a0=0,a1=0,a2=0,a3=0,a4=0,a5=0,a6=0,a7=0;

    for (int cb = 0; cb < len; cb += 64) {
        int t = cb + lane;
        unsigned wv = 0; int sr = 0;
        if (t < len) { wv = wg[start + t]; sr = es[start + t]; }
        int cl = len - cb; if (cl > 64) cl = 64;
        #pragma unroll 2
        for (int u = 0; u < cl; u += 8) {
            int e = u + g3;
            unsigned wp = (unsigned)__shfl((int)wv, e);
            int      sp = __shfl(sr, e);
            if (e < cl) {
                float2 wf = __half22float2(*(const __half2*)&wp);
                float wt = lowf ? wf.x : wf.y;
                size_t st = (size_t)((unsigned)sp >> BIN_SHIFT);
                const uint4 pk = *(const uint4*)(zh + st * 64 + q8 * 8);
                float2 f0 = __half22float2(*(const __half2*)&pk.x);
                float2 f1 = __half22float2(*(const __half2*)&pk.y);
                float2 f2 = __half22float2(*(const __half2*)&pk.z);
                float2 f3 = __half22float2(*(const __half2*)&pk.w);
                a0 = fmaf(wt, f0.x, a0); a1 = fmaf(wt, f0.y, a1);
                a2 = fmaf(wt, f1.x, a2); a3 = fmaf(wt, f1.y, a3);
                a4 = fmaf(wt, f2.x, a4); a5 = fmaf(wt, f2.y, a5);
                a6 = fmaf(wt, f3.x, a6); a7 = fmaf(wt, f3.y, a7);
            }
        }
    }
    #pragma unroll
    for (int off = 8; off <= 32; off <<= 1) {
        a0 += __shfl_xor(a0, off); a1 += __shfl_xor(a1, off);
        a2 += __shfl_xor(a2, off); a3 += __shfl_xor(a3, off);
        a4 += __shfl_xor(a4, off); a5 += __shfl_xor(a5, off);
        a6 += __shfl_xor(a6, off); a7 += __shfl_xor(a7, off);
    }
    if (g3 == 0) {
        float r = lowf ? rdL[node] : rdH[node];
        __half2 p0 = __floats2half2_rn(a0 * r, a1 * r);
        __half2 p1 = __floats2half2_rn(a2 * r, a3 * r);
        __half2 p2 = __floats2half2_rn(a4 * r, a5 * r);
        __half2 p3 = __floats2half2_rn(a6 * r, a7 * r);
        uint4 pk = make_uint4(*(unsigned*)&p0, *(unsigned*)&p1, *(unsigned*)&p2, *(unsigned*)&p3);
        // pos: L=bp->0, H=up->64 ; neg: L=un->96, H=bn->32
        int base = second ? (lowf ? 96 : 32) : (lowf ? 0 : 64);
        *(uint4*)(AGGH + (size_t)node * 128 + base + (q8 & 3) * 8) = pk;
    }
}

// ------------------------------ MLP 2 (MFMA) -------------------------------

__global__ __launch_bounds__(256) void mlp2_kernel(
        const __half* __restrict__ AGGH, const __half* __restrict__ zh,
        const __half* __restrict__ WPK2,
        const float* __restrict__ b2b, const float* __restrict__ b2u,
        float* __restrict__ out, int n, int ngrp) {
    int w = threadIdx.x >> 6, lane = threadIdx.x & 63;
    int fam = w & 1, l15 = lane & 15, lq = lane >> 4;

    half8 bfrag[3][2];
    #pragma unroll
    for (int kk = 0; kk < 3; ++kk)
        #pragma unroll
        for (int ct = 0; ct < 2; ++ct)
            bfrag[kk][ct] = *(const half8*)(WPK2 + (((fam * 3 + kk) * 2 + ct) << 9) + lane * 8);
    const float* bb = fam ? b2u : b2b;
    float bias0 = bb[l15], bias1 = bb[16 + l15];

    int grp = blockIdx.x * 2 + (w >> 1);
    if (grp >= ngrp) return;
    int gbase = grp * 16;
    int arow = gbase + l15; if (arow >= n) arow = n - 1;
    const __half* aggRow = AGGH + (size_t)arow * 128 + fam * 64;
    const __half* zRow   = zh   + (size_t)arow * 64 + fam * 32;

    f32x4 acc0 = {0.f, 0.f, 0.f, 0.f}, acc1 = {0.f, 0.f, 0.f, 0.f};
    #pragma unroll
    for (int kk = 0; kk < 2; ++kk) {
        half8 a = *(const half8*)(aggRow + kk * 32 + lq * 8);
        acc0 = __builtin_amdgcn_mfma_f32_16x16x32_f16(a, bfrag[kk][0], acc0, 0, 0, 0);
        acc1 = __builtin_amdgcn_mfma_f32_16x16x32_f16(a, bfrag[kk][1], acc1, 0, 0, 0);
    }
    {
        half8 a = *(const half8*)(zRow + lq * 8);
        acc0 = __builtin_amdgcn_mfma_f32_16x16x32_f16(a, bfrag[2][0], acc0, 0, 0, 0);
        acc1 = __builtin_amdgcn_mfma_f32_16x16x32_f16(a, bfrag[2][1], acc1, 0, 0, 0);
    }
    #pragma unroll
    for (int r = 0; r < 4; ++r) {
        int node = gbase + lq * 4 + r;
        if (node < n) {
            out[(size_t)node * 64 + fam * 32 + l15]      = tanhf(acc0[r] + bias0);
            out[(size_t)node * 64 + fam * 32 + 16 + l15] = tanhf(acc1[r] + bias1);
        }
    }
}

// ------------------------------ launcher -----------------------------------

extern "C" void kernel_launch(void* const* d_in, const int* in_sizes, int n_in,
                              void* d_out, int out_size, void* d_ws, size_t ws_size,
                              hipStream_t stream) {
    const float* x   = (const float*)d_in[0];
    const int*   pos = (const int*)d_in[1];
    const int*   neg = (const int*)d_in[2];
    const float* a1b = (const float*)d_in[3];
    const float* a1u = (const float*)d_in[4];
    const float* W1b = (const float*)d_in[5];
    const float* b1b = (const float*)d_in[6];
    const float* W1u = (const float*)d_in[7];
    const float* b1u = (const float*)d_in[8];
    const float* a2b = (const float*)d_in[9];
    const float* a2u = (const float*)d_in[10];
    const float* W2b = (const float*)d_in[11];
    const float* b2b = (const float*)d_in[12];
    const float* W2u = (const float*)d_in[13];
    const float* b2u = (const float*)d_in[14];
    float* out = (float*)d_out;

    const int n  = in_sizes[0] / 64;
    const int Ep = in_sizes[1] / 2;
    const int En = in_sizes[2] / 2;
    const int* ps = pos;  const int* pd = pos + Ep;
    const int* ns = neg;  const int* nd = neg + En;
    const int nbin = (n + BIN_SPAN - 1) >> BIN_SHIFT;
    const int ngrp = (n + 15) / 16;

    // ws layout (4-byte words)
    unsigned* W = (unsigned*)d_ws;
    size_t o = 0;
    float* S        = (float*)(W + o); o += 8 * (size_t)n;
    int*   rowptrP  = (int*)(W + o);   o += n + 1;
    int*   rowptrN  = (int*)(W + o);   o += n + 1;
    int*   binCntP  = (int*)(W + o);   o += nbin;
    int*   binCntN  = (int*)(W + o);   o += nbin;
    int*   binBaseP = (int*)(W + o);   o += nbin + 1;
    int*   binBaseN = (int*)(W + o);   o += nbin + 1;
    int*   gCur     = (int*)(W + o);   o += nbin;
    int*   esrcP    = (int*)(W + o);   o += Ep;
    int*   esrcN    = (int*)(W + o);   o += En;
    float* RDEN     = (float*)(W + o); o += 4 * (size_t)n;
    o = (o + 3) & ~(size_t)3;
    __half* XH      = (__half*)(W + o); o += 32 * (size_t)n;   // x rows fp16
    __half* ZH      = (__half*)(W + o); o += 32 * (size_t)n;   // z rows fp16
    float* WGT      = (float*)(W + o);  o += (size_t)Ep + En;
    o = (o + 3) & ~(size_t)3;
    __half* WPK1    = (__half*)(W + o); o += 4096;             // 8192 halves
    __half* WPK2    = (__half*)(W + o); o += 3072;             // 6144 halves
    __half* A2PK    = (__half*)(W + o); o += 256;              // 512 halves
    o = (o + 3) & ~(size_t)3;
    __half* AGGH    = (__half*)(W + o); o += 64 * (size_t)n;   // [n][128] fp16
    int*   binned   = (int*)AGGH;   // CSR-build scratch aliases AGGH/AGGH1
    __half* AGGH1   = AGGH;         // layer-1 agg rows [aggP|aggN]

    const int B = 256;
    const int aggBlocks = (2 * n + 3) / 4;
    const int mlpBlocks = (ngrp + 1) / 2;
    auto gcap = [](long t, int b) { long g = (t + b - 1) / b; return (int)(g < 2048 ? g : 2048); };

    // ---------------- CSR build + weight pack ----------------
    hipMemsetAsync(binCntP, 0, (size_t)nbin * sizeof(int), stream);
    hipMemsetAsync(binCntN, 0, (size_t)nbin * sizeof(int), stream);
    pack_weights_kernel<<<1, 256, 0, stream>>>(W1b, W1u, W2b, W2u, a2b, a2u,
                                               WPK1, WPK2, A2PK);
    bin_hist_kernel<<<gcap(Ep, B), B, 0, stream>>>(pd, Ep, binCntP, nbin);
    bin_hist_kernel<<<gcap(En, B), B, 0, stream>>>(nd, En, binCntN, nbin);

    scan_bins_kernel<<<1, 256, 0, stream>>>(binCntP, nbin, binBaseP, gCur, rowptrP, n, Ep);
    bin_scatter_kernel<<<(Ep + 4095) / 4096, 256, 0, stream>>>(ps, pd, Ep, binBaseP, gCur, binned, nbin);
    bin_finalize_kernel<<<nbin, 256, 0, stream>>>(binned, binBaseP, rowptrP, esrcP, n);

    scan_bins_kernel<<<1, 256, 0, stream>>>(binCntN, nbin, binBaseN, gCur, rowptrN, n, En);
    bin_scatter_kernel<<<(En + 4095) / 4096, 256, 0, stream>>>(ns, nd, En, binBaseN, gCur, binned, nbin);
    bin_finalize_kernel<<<nbin, 256, 0, stream>>>(binned, binBaseN, rowptrN, esrcN, n);

    // ---------------- Layer 1 ----------------
    scalars1_kernel<<<512, B, 0, stream>>>(x, a1b, a1u, S, XH, n);
    wgt1_kernel<<<nbin, 1024, 0, stream>>>(esrcP, binBaseP, esrcN, binBaseN, S,
                                           WGT, WGT + Ep, RDEN, RDEN + n, n);
    agg64_kernel<<<aggBlocks, 256, 0, stream>>>(
        rowptrP, esrcP, WGT,      RDEN,
        rowptrN, esrcN, WGT + Ep, RDEN + n,
        XH, AGGH1, n);
    mlp1f_kernel<<<mlpBlocks, 256, 0, stream>>>(AGGH1, XH, WPK1, A2PK,
                                                b1b, b1u, ZH, S, n, ngrp);

    // ---------------- Layer 2 ----------------
    wgt2_kernel<<<nbin, 1024, 0, stream>>>(esrcP, binBaseP, esrcN, binBaseN, S,
                                           (unsigned*)WGT, (unsigned*)WGT + Ep,
                                           RDEN, RDEN + n, RDEN + 2 * (size_t)n, RDEN + 3 * (size_t)n, n);
    agg32pair_kernel<<<aggBlocks, 256, 0, stream>>>(
        rowptrP, esrcP, (unsigned*)WGT,      RDEN,                 RDEN + n,
        rowptrN, esrcN, (unsigned*)WGT + Ep, RDEN + 2 * (size_t)n, RDEN + 3 * (size_t)n,
        ZH, AGGH, n);
    mlp2_kernel<<<mlpBlocks, 256, 0, stream>>>(AGGH, ZH, WPK2, b2b, b2u, out, n, ngrp);
}

// Round 10
// 438.293 us; speedup vs baseline: 1.3452x; 1.0470x over previous
//
#include <hip/hip_runtime.h>
#include <hip/hip_fp16.h>
#include <math.h>

// ---------------------------------------------------------------------------
// SNEA pipeline (MFMA MLPs, fp16 data paths, latency-optimized gathers):
//   CSR build: binned counting sort (bin = dst>>8, 392 bins), packed recs
//              src<<8|dstLocal; rowptr2[node] = int2{start,end}.
//   scalars1: layer-1 score projections + fp16 copy of x (XH).
//   wgt1/wgt2: per-edge softmax weights + rden per node (LDS per bin).
//   agg64:    pure gather, TWO independent accumulator sets so both unrolled
//             gather loads stay in flight -> fp16 AGGH1[n][128] = [aggP|aggN].
//   mlp1f:    MFMA 16x16x32_f16 MLP -> tanh -> ZH fp16 + layer-2 score dots.
//   agg32pair: paired gather over ZH -> fp16 AGGH[n][128] (bp|bn|up|un).
//   mlp2:     MFMA [16x96]@[96x32] -> tanh -> out.
// No segment-max anywhere: scores ~N(0,1), unstabilized exp is f32-safe and
// mathematically identical to the max-subtracted softmax.
// ---------------------------------------------------------------------------

#define BIN_SHIFT 8
#define BIN_SPAN  256
#define NBIN_MAX  512          // n <= 131072; src fits 24 bits

typedef _Float16 half8 __attribute__((ext_vector_type(8)));
typedef float f32x4 __attribute__((ext_vector_type(4)));

// ----------------------------- CSR build ----------------------------------

__global__ __launch_bounds__(256) void bin_hist_kernel(const int* __restrict__ dst, int E,
                                                       int* __restrict__ binCnt, int nbin) {
    __shared__ int lc[NBIN_MAX];
    for (int i = threadIdx.x; i < nbin; i += 256) lc[i] = 0;
    __syncthreads();
    int i = blockIdx.x * blockDim.x + threadIdx.x;
    int stride = gridDim.x * blockDim.x;
    for (; i < E; i += stride) atomicAdd(&lc[dst[i] >> BIN_SHIFT], 1);
    __syncthreads();
    for (int b = threadIdx.x; b < nbin; b += 256)
        if (lc[b]) atomicAdd(&binCnt[b], lc[b]);
}

// one block of 512 threads: exclusive scan binCnt -> binBase; zero gCursor.
__global__ __launch_bounds__(512) void scan_bins_kernel(const int* __restrict__ binCnt, int nbin,
                                                        int* __restrict__ binBase,
                                                        int* __restrict__ gCursor) {
    __shared__ int sd[512];
    int tid = threadIdx.x;
    int v = (tid < nbin) ? binCnt[tid] : 0;
    sd[tid] = v; __syncthreads();
    for (int off = 1; off < 512; off <<= 1) {
        int t = (tid >= off) ? sd[tid - off] : 0;
        __syncthreads();
        sd[tid] += t;
        __syncthreads();
    }
    if (tid < nbin) { binBase[tid] = sd[tid] - v; gCursor[tid] = 0; }
    if (tid == nbin - 1) binBase[nbin] = sd[tid];
}

__global__ __launch_bounds__(256) void bin_scatter_kernel(
        const int* __restrict__ src, const int* __restrict__ dst, int E,
        const int* __restrict__ binBase, int* __restrict__ gCursor,
        int* __restrict__ binned, int nbin) {
    __shared__ int lc[NBIN_MAX];
    __shared__ int lbase[NBIN_MAX];
    for (int i = threadIdx.x; i < nbin; i += 256) lc[i] = 0;
    __syncthreads();
    int base0 = blockIdx.x * 4096 + threadIdx.x * 16;
    int rank[16], bn[16];
    #pragma unroll
    for (int k = 0; k < 16; ++k) {
        int i = base0 + k;
        if (i < E) {
            int b = dst[i] >> BIN_SHIFT;
            bn[k] = b;
            rank[k] = atomicAdd(&lc[b], 1);
        }
    }
    __syncthreads();
    for (int b = threadIdx.x; b < nbin; b += 256)
        if (lc[b]) lbase[b] = atomicAdd(&gCursor[b], lc[b]);
    __syncthreads();
    #pragma unroll
    for (int k = 0; k < 16; ++k) {
        int i = base0 + k;
        if (i < E) {
            int b = bn[k];
            int pos = binBase[b] + lbase[b] + rank[k];
            binned[pos] = (src[i] << BIN_SHIFT) | (dst[i] & (BIN_SPAN - 1));
        }
    }
}

// one block per bin (256 nodes): hist -> scan -> rowptr2{start,end} -> scatter.
__global__ __launch_bounds__(256) void bin_finalize_kernel(
        const int* __restrict__ binned, const int* __restrict__ binBase,
        int2* __restrict__ rowptr2, int* __restrict__ esrc, int n) {
    __shared__ int hist[BIN_SPAN];
    __shared__ int curs[BIN_SPAN];
    __shared__ int psum[256];
    int b = blockIdx.x, tid = threadIdx.x;
    int lo = binBase[b], hi = binBase[b + 1];
    int nodeBase = b << BIN_SHIFT;
    hist[tid] = 0;
    __syncthreads();
    for (int i = lo + tid; i < hi; i += 256)
        atomicAdd(&hist[binned[i] & (BIN_SPAN - 1)], 1);
    __syncthreads();
    int a0 = hist[tid];
    psum[tid] = a0; __syncthreads();
    for (int off = 1; off < 256; off <<= 1) {
        int t = (tid >= off) ? psum[tid - off] : 0;
        __syncthreads();
        psum[tid] += t;
        __syncthreads();
    }
    int excl = psum[tid] - a0;
    curs[tid] = excl;
    {
        int node = nodeBase + tid;
        if (node < n) rowptr2[node] = make_int2(lo + excl, lo + excl + a0);
    }
    __syncthreads();
    for (int i = lo + tid; i < hi; i += 256) {
        int rec = binned[i];
        int slot = lo + atomicAdd(&curs[rec & (BIN_SPAN - 1)], 1);
        esrc[slot] = rec;      // keep packed
    }
}

// --------------------------- scalars (layer 1) ------------------------------

__global__ __launch_bounds__(256) void scalars1_kernel(
        const float* __restrict__ x,
        const float* __restrict__ a1b, const float* __restrict__ a1u,
        float* __restrict__ S, __half* __restrict__ xh, int n) {
    __shared__ float sA[256];
    for (int k = threadIdx.x; k < 256; k += blockDim.x)
        sA[k] = (k < 128) ? a1b[k] : a1u[k - 128];
    __syncthreads();
    int grp = threadIdx.x >> 4, l = threadIdx.x & 15;
    for (int row = blockIdx.x * 16 + grp; row < n; row += gridDim.x * 16) {
        const float4 v = *(const float4*)(x + (size_t)row * 64 + l * 4);
        __half2 h0 = __floats2half2_rn(v.x, v.y);
        __half2 h1 = __floats2half2_rn(v.z, v.w);
        uint2 pk = make_uint2(*(unsigned*)&h0, *(unsigned*)&h1);
        *(uint2*)(xh + (size_t)row * 64 + l * 4) = pk;
        const float4 A0 = *(const float4*)(sA + l * 4);
        const float4 A1 = *(const float4*)(sA + 64 + l * 4);
        const float4 A2 = *(const float4*)(sA + 128 + l * 4);
        const float4 A3 = *(const float4*)(sA + 192 + l * 4);
        float p0 = fmaf(v.x, A0.x, fmaf(v.y, A0.y, fmaf(v.z, A0.z, v.w * A0.w)));
        float p1 = fmaf(v.x, A1.x, fmaf(v.y, A1.y, fmaf(v.z, A1.z, v.w * A1.w)));
        float p2 = fmaf(v.x, A2.x, fmaf(v.y, A2.y, fmaf(v.z, A2.z, v.w * A2.w)));
        float p3 = fmaf(v.x, A3.x, fmaf(v.y, A3.y, fmaf(v.z, A3.z, v.w * A3.w)));
        #pragma unroll
        for (int off = 1; off < 16; off <<= 1) {
            p0 += __shfl_xor(p0, off);
            p1 += __shfl_xor(p1, off);
            p2 += __shfl_xor(p2, off);
            p3 += __shfl_xor(p3, off);
        }
        if (l == 0) {
            S[row] = p0;
            S[(size_t)n + row] = p1;
            S[2 * (size_t)n + row] = p2;
            S[3 * (size_t)n + row] = p3;
        }
    }
}

// ----------------------- per-edge weights + den ----------------------------

__global__ __launch_bounds__(512) void wgt1_kernel(
        const int* __restrict__ esrcP, const int* __restrict__ binBaseP,
        const int* __restrict__ esrcN, const int* __restrict__ binBaseN,
        const float* __restrict__ S,
        float* __restrict__ wgtP, float* __restrict__ wgtN,
        float* __restrict__ rdenP, float* __restrict__ rdenN, int n) {
    __shared__ float dP[BIN_SPAN], dN[BIN_SPAN];
    int b = blockIdx.x, tid = threadIdx.x;
    if (tid < BIN_SPAN) { dP[tid] = 0.f; dN[tid] = 0.f; }
    __syncthreads();
    int nodeBase = b << BIN_SHIFT;
    const float* siP = S;                     const float* sjP = S + (size_t)n;
    const float* siN = S + 2 * (size_t)n;     const float* sjN = S + 3 * (size_t)n;
    for (int i = binBaseP[b] + tid, hi = binBaseP[b + 1]; i < hi; i += 512) {
        int rec = esrcP[i];
        int src = (int)((unsigned)rec >> BIN_SHIFT);
        int dl  = rec & (BIN_SPAN - 1);
        float w = __expf(siP[nodeBase + dl] + sjP[src]);
        wgtP[i] = w;
        atomicAdd(&dP[dl], w);
    }
    for (int i = binBaseN[b] + tid, hi = binBaseN[b + 1]; i < hi; i += 512) {
        int rec = esrcN[i];
        int src = (int)((unsigned)rec >> BIN_SHIFT);
        int dl  = rec & (BIN_SPAN - 1);
        float w = __expf(siN[nodeBase + dl] + sjN[src]);
        wgtN[i] = w;
        atomicAdd(&dN[dl], w);
    }
    __syncthreads();
    if (tid < BIN_SPAN) {
        int node = nodeBase + tid;
        if (node < n) {
            rdenP[node] = 1.0f / fmaxf(dP[tid], 1e-16f);
            rdenN[node] = 1.0f / fmaxf(dN[tid], 1e-16f);
        }
    }
}

// pos: L=bp(S0,S1) H=up(S4,S5).  neg: L=un(S6,S7) H=bn(S2,S3).
__global__ __launch_bounds__(512) void wgt2_kernel(
        const int* __restrict__ esrcP, const int* __restrict__ binBaseP,
        const int* __restrict__ esrcN, const int* __restrict__ binBaseN,
        const float* __restrict__ S,
        unsigned* __restrict__ wgtP, unsigned* __restrict__ wgtN,
        float* __restrict__ rdenPL, float* __restrict__ rdenPH,
        float* __restrict__ rdenNL, float* __restrict__ rdenNH, int n) {
    __shared__ float dPL[BIN_SPAN], dPH[BIN_SPAN], dNL[BIN_SPAN], dNH[BIN_SPAN];
    int b = blockIdx.x, tid = threadIdx.x;
    if (tid < BIN_SPAN) { dPL[tid] = 0.f; dPH[tid] = 0.f; dNL[tid] = 0.f; dNH[tid] = 0.f; }
    __syncthreads();
    int nodeBase = b << BIN_SHIFT;
    const float* S0 = S;                   const float* S1 = S + (size_t)n;
    const float* S2 = S + 2 * (size_t)n;   const float* S3 = S + 3 * (size_t)n;
    const float* S4 = S + 4 * (size_t)n;   const float* S5 = S + 5 * (size_t)n;
    const float* S6 = S + 6 * (size_t)n;   const float* S7 = S + 7 * (size_t)n;
    for (int i = binBaseP[b] + tid, hi = binBaseP[b + 1]; i < hi; i += 512) {
        int rec = esrcP[i];
        int src = (int)((unsigned)rec >> BIN_SHIFT);
        int dl  = rec & (BIN_SPAN - 1);
        float wL = __expf(S0[nodeBase + dl] + S1[src]);   // bp
        float wH = __expf(S4[nodeBase + dl] + S5[src]);   // up
        __half2 h = __floats2half2_rn(wL, wH);
        wgtP[i] = *(unsigned*)&h;
        atomicAdd(&dPL[dl], wL);
        atomicAdd(&dPH[dl], wH);
    }
    for (int i = binBaseN[b] + tid, hi = binBaseN[b + 1]; i < hi; i += 512) {
        int rec = esrcN[i];
        int src = (int)((unsigned)rec >> BIN_SHIFT);
        int dl  = rec & (BIN_SPAN - 1);
        float wL = __expf(S6[nodeBase + dl] + S7[src]);   // un
        float wH = __expf(S2[nodeBase + dl] + S3[src]);   // bn
        __half2 h = __floats2half2_rn(wL, wH);
        wgtN[i] = *(unsigned*)&h;
        atomicAdd(&dNL[dl], wL);
        atomicAdd(&dNH[dl], wH);
    }
    __syncthreads();
    if (tid < BIN_SPAN) {
        int node = nodeBase + tid;
        if (node < n) {
            rdenPL[node] = 1.0f / fmaxf(dPL[tid], 1e-16f);
            rdenPH[node] = 1.0f / fmaxf(dPH[tid], 1e-16f);
            rdenNL[node] = 1.0f / fmaxf(dNL[tid], 1e-16f);
            rdenNH[node] = 1.0f / fmaxf(dNH[tid], 1e-16f);
        }
    }
}

// --------------------- layer 1 aggregation (pure gather) -------------------

__global__ __launch_bounds__(256) void agg64_kernel(
        const int2* __restrict__ rpA, const int* __restrict__ esA,
        const float* __restrict__ wA, const float* __restrict__ rdA,
        const int2* __restrict__ rpB, const int* __restrict__ esB,
        const float* __restrict__ wB, const float* __restrict__ rdB,
        const __half* __restrict__ xh, __half* __restrict__ AGGH1, int n) {
    int w = threadIdx.x >> 6, lane = threadIdx.x & 63;
    int idx = blockIdx.x * 4 + w;
    if (idx >= 2 * n) return;
    bool second = idx >= n;
    int node = second ? idx - n : idx;
    const int2*  rp = second ? rpB : rpA;
    const int*   es = second ? esB : esA;
    const float* wg = second ? wB : wA;
    float r = (second ? rdB : rdA)[node];

    int2 se = rp[node];
    int start = se.x, len = se.y - se.x;
    int g3 = lane >> 3, q8 = lane & 7;
    float A0=0,A1=0,A2=0,A3=0,A4=0,A5=0,A6=0,A7=0;   // even steps
    float B0=0,B1=0,B2=0,B3=0,B4=0,B5=0,B6=0,B7=0;   // odd steps

    for (int cb = 0; cb < len; cb += 64) {
        int t = cb + lane;
        float wv = 0.f; int sr = 0;
        if (t < len) { wv = wg[start + t]; sr = es[start + t]; }
        int cl = len - cb; if (cl > 64) cl = 64;
        #pragma unroll 2
        for (int u = 0; u < cl; u += 16) {
            int e0 = u + g3, e1 = u + 8 + g3;
            float wt0 = __shfl(wv, e0);
            int   sp0 = __shfl(sr, e0);
            float wt1 = __shfl(wv, e1);
            int   sp1 = __shfl(sr, e1);
            bool v0 = e0 < cl, v1 = e1 < cl;
            uint4 pk0, pk1;
            if (v0) pk0 = *(const uint4*)(xh + (size_t)((unsigned)sp0 >> BIN_SHIFT) * 64 + q8 * 8);
            if (v1) pk1 = *(const uint4*)(xh + (size_t)((unsigned)sp1 >> BIN_SHIFT) * 64 + q8 * 8);
            if (v0) {
                float2 f0 = __half22float2(*(const __half2*)&pk0.x);
                float2 f1 = __half22float2(*(const __half2*)&pk0.y);
                float2 f2 = __half22float2(*(const __half2*)&pk0.z);
                float2 f3 = __half22float2(*(const __half2*)&pk0.w);
                A0 = fmaf(wt0, f0.x, A0); A1 = fmaf(wt0, f0.y, A1);
                A2 = fmaf(wt0, f1.x, A2); A3 = fmaf(wt0, f1.y, A3);
                A4 = fmaf(wt0, f2.x, A4); A5 = fmaf(wt0, f2.y, A5);
                A6 = fmaf(wt0, f3.x, A6); A7 = fmaf(wt0, f3.y, A7);
            }
            if (v1) {
                float2 f0 = __half22float2(*(const __half2*)&pk1.x);
                float2 f1 = __half22float2(*(const __half2*)&pk1.y);
                float2 f2 = __half22float2(*(const __half2*)&pk1.z);
                float2 f3 = __half22float2(*(const __half2*)&pk1.w);
                B0 = fmaf(wt1, f0.x, B0); B1 = fmaf(wt1, f0.y, B1);
                B2 = fmaf(wt1, f1.x, B2); B3 = fmaf(wt1, f1.y, B3);
                B4 = fmaf(wt1, f2.x, B4); B5 = fmaf(wt1, f2.y, B5);
                B6 = fmaf(wt1, f3.x, B6); B7 = fmaf(wt1, f3.y, B7);
            }
        }
    }
    float a0=A0+B0, a1=A1+B1, a2=A2+B2, a3=A3+B3;
    float a4=A4+B4, a5=A5+B5, a6=A6+B6, a7=A7+B7;
    #pragma unroll
    for (int off = 8; off <= 32; off <<= 1) {
        a0 += __shfl_xor(a0, off); a1 += __shfl_xor(a1, off);
        a2 += __shfl_xor(a2, off); a3 += __shfl_xor(a3, off);
        a4 += __shfl_xor(a4, off); a5 += __shfl_xor(a5, off);
        a6 += __shfl_xor(a6, off); a7 += __shfl_xor(a7, off);
    }
    if (g3 == 0) {
        __half2 p0 = __floats2half2_rn(a0 * r, a1 * r);
        __half2 p1 = __floats2half2_rn(a2 * r, a3 * r);
        __half2 p2 = __floats2half2_rn(a4 * r, a5 * r);
        __half2 p3 = __floats2half2_rn(a6 * r, a7 * r);
        uint4 pk = make_uint4(*(unsigned*)&p0, *(unsigned*)&p1, *(unsigned*)&p2, *(unsigned*)&p3);
        *(uint4*)(AGGH1 + (size_t)node * 128 + (second ? 64 : 0) + q8 * 8) = pk;
    }
}

// --------------------- weight packing for MFMA MLPs ------------------------

__global__ __launch_bounds__(256) void pack_weights_kernel(
        const float* __restrict__ W1b, const float* __restrict__ W1u,
        const float* __restrict__ W2b, const float* __restrict__ W2u,
        const float* __restrict__ a2b, const float* __restrict__ a2u,
        __half* __restrict__ WPK1, __half* __restrict__ WPK2,
        __half* __restrict__ A2PK) {
    int t = threadIdx.x;
    for (int i = t; i < 8192; i += 256) {
        int j = i & 7, lane = (i >> 3) & 63, ct = (i >> 9) & 1, kk = (i >> 10) & 3, fam = i >> 12;
        const float* Wx = fam ? W1u : W1b;
        int k = kk * 32 + ((lane >> 4) << 3) + j;
        int col = ct * 16 + (lane & 15);
        WPK1[i] = __float2half(Wx[k * 32 + col]);
    }
    for (int i = t; i < 6144; i += 256) {
        int j = i & 7, lane = (i >> 3) & 63, ct = (i >> 9) & 1;
        int rest = i >> 10;                 // (fam*3 + kk)
        int kk = rest % 3, fam = rest / 3;
        const float* Wx = fam ? W2u : W2b;
        int k = kk * 32 + ((lane >> 4) << 3) + j;
        int col = ct * 16 + (lane & 15);
        WPK2[i] = __float2half(Wx[k * 32 + col]);
    }
    for (int i = t; i < 512; i += 256) {
        int j = i & 7, lane = i >> 3;
        int q = lane & 15, k = ((lane >> 4) << 3) + j;
        float v = 0.f;
        if (q == 0) v = a2b[k];
        else if (q == 1) v = a2b[32 + k];
        else if (q == 2) v = a2u[k];
        else if (q == 3) v = a2u[32 + k];
        A2PK[i] = __float2half(v);
    }
}

// ---------------- layer 1 MLP (MFMA) + tanh + layer-2 scores ---------------

#define ZPITCH 40   // halves; 80B rows keep uint4/half8 accesses 16B-aligned

__global__ __launch_bounds__(256) void mlp1f_kernel(
        const __half* __restrict__ AGGH1, const __half* __restrict__ xh,
        const __half* __restrict__ WPK1, const __half* __restrict__ A2PK,
        const float* __restrict__ b1b, const float* __restrict__ b1u,
        __half* __restrict__ zh, float* __restrict__ S, int n, int ngrp) {
    __shared__ __half zLds[4][16][ZPITCH];
    int w = threadIdx.x >> 6, lane = threadIdx.x & 63;
    int fam = w & 1, l15 = lane & 15, lq = lane >> 4;

    half8 bfrag[4][2];
    #pragma unroll
    for (int kk = 0; kk < 4; ++kk)
        #pragma unroll
        for (int ct = 0; ct < 2; ++ct)
            bfrag[kk][ct] = *(const half8*)(WPK1 + (((fam * 4 + kk) * 2 + ct) << 9) + lane * 8);
    half8 a2frag = *(const half8*)(A2PK + lane * 8);
    const float* bb = fam ? b1u : b1b;
    float bias0 = bb[l15], bias1 = bb[16 + l15];

    int grp = blockIdx.x * 2 + (w >> 1);
    if (grp >= ngrp) return;
    int gbase = grp * 16;
    int arow = gbase + l15; if (arow >= n) arow = n - 1;
    const __half* aggRow = AGGH1 + (size_t)arow * 128 + fam * 64;
    const __half* xRow   = xh   + (size_t)arow * 64;

    f32x4 acc0 = {0.f, 0.f, 0.f, 0.f}, acc1 = {0.f, 0.f, 0.f, 0.f};
    #pragma unroll
    for (int kk = 0; kk < 2; ++kk) {
        half8 a = *(const half8*)(aggRow + kk * 32 + lq * 8);
        acc0 = __builtin_amdgcn_mfma_f32_16x16x32_f16(a, bfrag[kk][0], acc0, 0, 0, 0);
        acc1 = __builtin_amdgcn_mfma_f32_16x16x32_f16(a, bfrag[kk][1], acc1, 0, 0, 0);
    }
    #pragma unroll
    for (int kk = 2; kk < 4; ++kk) {
        half8 a = *(const half8*)(xRow + (kk - 2) * 32 + lq * 8);
        acc0 = __builtin_amdgcn_mfma_f32_16x16x32_f16(a, bfrag[kk][0], acc0, 0, 0, 0);
        acc1 = __builtin_amdgcn_mfma_f32_16x16x32_f16(a, bfrag[kk][1], acc1, 0, 0, 0);
    }
    #pragma unroll
    for (int r = 0; r < 4; ++r) {
        int row = lq * 4 + r;
        zLds[w][row][l15]      = __float2half(tanhf(acc0[r] + bias0));
        zLds[w][row][16 + l15] = __float2half(tanhf(acc1[r] + bias1));
    }
    {
        int node = lane >> 2, chunk = lane & 3;
        uint4 v = *(const uint4*)(&zLds[w][node][chunk * 8]);
        int gn = gbase + node;
        if (gn < n) *(uint4*)(zh + (size_t)gn * 64 + fam * 32 + chunk * 8) = v;
    }
    {
        half8 a = *(const half8*)(&zLds[w][l15][lq * 8]);
        f32x4 sacc = {0.f, 0.f, 0.f, 0.f};
        sacc = __builtin_amdgcn_mfma_f32_16x16x32_f16(a, a2frag, sacc, 0, 0, 0);
        if (l15 < 4) {
            const int mapB[4] = {0, 1, 6, 7};   // zb: S0,S1,S6,S7
            const int mapU[4] = {2, 3, 4, 5};   // zu: S2,S3,S4,S5
            int st = fam ? mapU[l15] : mapB[l15];
            #pragma unroll
            for (int r = 0; r < 4; ++r) {
                int node = gbase + lq * 4 + r;
                if (node < n) S[(size_t)st * n + node] = sacc[r];
            }
        }
    }
}

// ------------------- layer 2 aggregation (paired gather) -------------------

// AGGH row layout per node: [bp(32) | bn(32) | up(32) | un(32)] fp16.
__global__ __launch_bounds__(256) void agg32pair_kernel(
        const int2* __restrict__ rpA, const int* __restrict__ esA,
        const unsigned* __restrict__ wA,
        const float* __restrict__ rdLA, const float* __restrict__ rdHA,
        const int2* __restrict__ rpB, const int* __restrict__ esB,
        const unsigned* __restrict__ wB,
        const float* __restrict__ rdLB, const float* __restrict__ rdHB,
        const __half* __restrict__ zh, __half* __restrict__ AGGH, int n) {
    int w = threadIdx.x >> 6, lane = threadIdx.x & 63;
    int idx = blockIdx.x * 4 + w;
    if (idx >= 2 * n) return;
    bool second = idx >= n;
    int node = second ? idx - n : idx;
    const int2*     rp  = second ? rpB  : rpA;
    const int*      es  = second ? esB  : esA;
    const unsigned* wg  = second ? wB   : wA;
    const float*    rdL = second ? rdLB : rdLA;
    const float*    rdH = second ? rdHB : rdHA;

    int2 se = rp[node];
    int start = se.x, len = se.y - se.x;
    int g3 = lane >> 3, q8 = lane & 7;
    bool lowf = q8 < 4;
    float A0=0,A1=0,A2=0,A3=0,A4=0,A5=0,A6=0,A7=0;
    float B0=0,B1=0,B2=0,B3=0,B4=0,B5=0,B6=0,B7=0;

    for (int cb = 0; cb < len; cb += 64) {
        int t = cb + lane;
        unsigned wv = 0; int sr = 0;
        if (t < len) { wv = wg[start + t]; sr = es[start + t]; }
        int cl = len - cb; if (cl > 64) cl = 64;
        #pragma unroll 2
        for (int u = 0; u < cl; u += 16) {
            int e0 = u + g3, e1 = u + 8 + g3;
            unsigned wp0 = (unsigned)__shfl((int)wv, e0);
            int      sp0 = __shfl(sr, e0);
            unsigned wp1 = (unsigned)__shfl((int)wv, e1);
            int      sp1 = __shfl(sr, e1);
            bool v0 = e0 < cl, v1 = e1 < cl;
            uint4 pk0, pk1;
            if (v0) pk0 = *(const uint4*)(zh + (size_t)((unsigned)sp0 >> BIN_SHIFT) * 64 + q8 * 8);
            if (v1) pk1 = *(const uint4*)(zh + (size_t)((unsigned)sp1 >> BIN_SHIFT) * 64 + q8 * 8);
            if (v0) {
                float2 wf = __half22float2(*(const __half2*)&wp0);
                float wt = lowf ? wf.x : wf.y;
                float2 f0 = __half22float2(*(const __half2*)&pk0.x);
                float2 f1 = __half22float2(*(const __half2*)&pk0.y);
                float2 f2 = __half22float2(*(const __half2*)&pk0.z);
                float2 f3 = __half22float2(*(const __half2*)&pk0.w);
                A0 = fmaf(wt, f0.x, A0); A1 = fmaf(wt, f0.y, A1);
                A2 = fmaf(wt, f1.x, A2); A3 = fmaf(wt, f1.y, A3);
                A4 = fmaf(wt, f2.x, A4); A5 = fmaf(wt, f2.y, A5);
                A6 = fmaf(wt, f3.x, A6); A7 = fmaf(wt, f3.y, A7);
            }
            if (v1) {
                float2 wf = __half22float2(*(const __half2*)&wp1);
                float wt = lowf ? wf.x : wf.y;
                float2 f0 = __half22float2(*(const __half2*)&pk1.x);
                float2 f1 = __half22float2(*(const __half2*)&pk1.y);
                float2 f2 = __half22float2(*(const __half2*)&pk1.z);
                float2 f3 = __half22float2(*(const __half2*)&pk1.w);
                B0 = fmaf(wt, f0.x, B0); B1 = fmaf(wt, f0.y, B1);
                B2 = fmaf(wt, f1.x, B2); B3 = fmaf(wt, f1.y, B3);
                B4 = fmaf(wt, f2.x, B4); B5 = fmaf(wt, f2.y, B5);
                B6 = fmaf(wt, f3.x, B6); B7 = fmaf(wt, f3.y, B7);
            }
        }
    }
    float a0=A0+B0, a1=A1+B1, a2=A2+B2, a3=A3+B3;
    float a4=A4+B4, a5=A5+B5, a6=A6+B6, a7=A7+B7;
    #pragma unroll
    for (int off = 8; off <= 32; off <<= 1) {
        a0 += __shfl_xor(a0, off); a1 += __shfl_xor(a1, off);
        a2 += __shfl_xor(a2, off); a3 += __shfl_xor(a3, off);
        a4 += __shfl_xor(a4, off); a5 += __shfl_xor(a5, off);
        a6 += __shfl_xor(a6, off); a7 += __shfl_xor(a7, off);
    }
    if (g3 == 0) {
        float r = lowf ? rdL[node] : rdH[node];
        __half2 p0 = __floats2half2_rn(a0 * r, a1 * r);
        __half2 p1 = __floats2half2_rn(a2 * r, a3 * r);
        __half2 p2 = __floats2half2_rn(a4 * r, a5 * r);
        __half2 p3 = __floats2half2_rn(a6 * r, a7 * r);
        uint4 pk = make_uint4(*(unsigned*)&p0, *(unsigned*)&p1, *(unsigned*)&p2, *(unsigned*)&p3);
        // pos: L=bp->0, H=up->64 ; neg: L=un->96, H=bn->32
        int base = second ? (lowf ? 96 : 32) : (lowf ? 0 : 64);
        *(uint4*)(AGGH + (size_t)node * 128 + base + (q8 & 3) * 8) = pk;
    }
}

// ------------------------------ MLP 2 (MFMA) -------------------------------

__global__ __launch_bounds__(256) void mlp2_kernel(
        const __half* __restrict__ AGGH, const __half* __restrict__ zh,
        const __half* __restrict__ WPK2,
        const float* __restrict__ b2b, const float* __restrict__ b2u,
        float* __restrict__ out, int n, int ngrp) {
    int w = threadIdx.x >> 6, lane = threadIdx.x & 63;
    int fam = w & 1, l15 = lane & 15, lq = lane >> 4;

    half8 bfrag[3][2];
    #pragma unroll
    for (int kk = 0; kk < 3; ++kk)
        #pragma unroll
        for (int ct = 0; ct < 2; ++ct)
            bfrag[kk][ct] = *(const half8*)(WPK2 + (((fam * 3 + kk) * 2 + ct) << 9) + lane * 8);
    const float* bb = fam ? b2u : b2b;
    float bias0 = bb[l15], bias1 = bb[16 + l15];

    int grp = blockIdx.x * 2 + (w >> 1);
    if (grp >= ngrp) return;
    int gbase = grp * 16;
    int arow = gbase + l15; if (arow >= n) arow = n - 1;
    const __half* aggRow = AGGH + (size_t)arow * 128 + fam * 64;
    const __half* zRow   = zh   + (size_t)arow * 64 + fam * 32;

    f32x4 acc0 = {0.f, 0.f, 0.f, 0.f}, acc1 = {0.f, 0.f, 0.f, 0.f};
    #pragma unroll
    for (int kk = 0; kk < 2; ++kk) {
        half8 a = *(const half8*)(aggRow + kk * 32 + lq * 8);
        acc0 = __builtin_amdgcn_mfma_f32_16x16x32_f16(a, bfrag[kk][0], acc0, 0, 0, 0);
        acc1 = __builtin_amdgcn_mfma_f32_16x16x32_f16(a, bfrag[kk][1], acc1, 0, 0, 0);
    }
    {
        half8 a = *(const half8*)(zRow + lq * 8);
        acc0 = __builtin_amdgcn_mfma_f32_16x16x32_f16(a, bfrag[2][0], acc0, 0, 0, 0);
        acc1 = __builtin_amdgcn_mfma_f32_16x16x32_f16(a, bfrag[2][1], acc1, 0, 0, 0);
    }
    #pragma unroll
    for (int r = 0; r < 4; ++r) {
        int node = gbase + lq * 4 + r;
        if (node < n) {
            out[(size_t)node * 64 + fam * 32 + l15]      = tanhf(acc0[r] + bias0);
            out[(size_t)node * 64 + fam * 32 + 16 + l15] = tanhf(acc1[r] + bias1);
        }
    }
}

// ------------------------------ launcher -----------------------------------

extern "C" void kernel_launch(void* const* d_in, const int* in_sizes, int n_in,
                              void* d_out, int out_size, void* d_ws, size_t ws_size,
                              hipStream_t stream) {
    const float* x   = (const float*)d_in[0];
    const int*   pos = (const int*)d_in[1];
    const int*   neg = (const int*)d_in[2];
    const float* a1b = (const float*)d_in[3];
    const float* a1u = (const float*)d_in[4];
    const float* W1b = (const float*)d_in[5];
    const float* b1b = (const float*)d_in[6];
    const float* W1u = (const float*)d_in[7];
    const float* b1u = (const float*)d_in[8];
    const float* a2b = (const float*)d_in[9];
    const float* a2u = (const float*)d_in[10];
    const float* W2b = (const float*)d_in[11];
    const float* b2b = (const float*)d_in[12];
    const float* W2u = (const float*)d_in[13];
    const float* b2u = (const float*)d_in[14];
    float* out = (float*)d_out;

    const int n  = in_sizes[0] / 64;
    const int Ep = in_sizes[1] / 2;
    const int En = in_sizes[2] / 2;
    const int* ps = pos;  const int* pd = pos + Ep;
    const int* ns = neg;  const int* nd = neg + En;
    const int nbin = (n + BIN_SPAN - 1) >> BIN_SHIFT;   // 391 for n=100000
    const int ngrp = (n + 15) / 16;

    // ws layout (4-byte words)
    unsigned* W = (unsigned*)d_ws;
    size_t o = 0;
    float* S        = (float*)(W + o); o += 8 * (size_t)n;
    int2*  rowptrP  = (int2*)(W + o);  o += 2 * (size_t)n;
    int2*  rowptrN  = (int2*)(W + o);  o += 2 * (size_t)n;
    int*   binCntP  = (int*)(W + o);   o += nbin;
    int*   binCntN  = (int*)(W + o);   o += nbin;
    int*   binBaseP = (int*)(W + o);   o += nbin + 1;
    int*   binBaseN = (int*)(W + o);   o += nbin + 1;
    int*   gCur     = (int*)(W + o);   o += nbin;
    int*   esrcP    = (int*)(W + o);   o += Ep;
    int*   esrcN    = (int*)(W + o);   o += En;
    float* RDEN     = (float*)(W + o); o += 4 * (size_t)n;
    o = (o + 3) & ~(size_t)3;
    __half* XH      = (__half*)(W + o); o += 32 * (size_t)n;   // x rows fp16
    __half* ZH      = (__half*)(W + o); o += 32 * (size_t)n;   // z rows fp16
    float* WGT      = (float*)(W + o);  o += (size_t)Ep + En;
    o = (o + 3) & ~(size_t)3;
    __half* WPK1    = (__half*)(W + o); o += 4096;
    __half* WPK2    = (__half*)(W + o); o += 3072;
    __half* A2PK    = (__half*)(W + o); o += 256;
    o = (o + 3) & ~(size_t)3;
    __half* AGGH    = (__half*)(W + o); o += 64 * (size_t)n;   // [n][128] fp16
    int*   binned   = (int*)AGGH;   // CSR-build scratch aliases AGGH/AGGH1
    __half* AGGH1   = AGGH;         // layer-1 agg rows [aggP|aggN]

    const int B = 256;
    const int aggBlocks = (2 * n + 3) / 4;
    const int mlpBlocks = (ngrp + 1) / 2;
    auto gcap = [](long t, int b) { long g = (t + b - 1) / b; return (int)(g < 2048 ? g : 2048); };

    // ---------------- CSR build + weight pack ----------------
    hipMemsetAsync(binCntP, 0, (size_t)nbin * sizeof(int), stream);
    hipMemsetAsync(binCntN, 0, (size_t)nbin * sizeof(int), stream);
    pack_weights_kernel<<<1, 256, 0, stream>>>(W1b, W1u, W2b, W2u, a2b, a2u,
                                               WPK1, WPK2, A2PK);
    bin_hist_kernel<<<gcap(Ep, B), B, 0, stream>>>(pd, Ep, binCntP, nbin);
    bin_hist_kernel<<<gcap(En, B), B, 0, stream>>>(nd, En, binCntN, nbin);

    scan_bins_kernel<<<1, 512, 0, stream>>>(binCntP, nbin, binBaseP, gCur);
    bin_scatter_kernel<<<(Ep + 4095) / 4096, 256, 0, stream>>>(ps, pd, Ep, binBaseP, gCur, binned, nbin);
    bin_finalize_kernel<<<nbin, 256, 0, stream>>>(binned, binBaseP, rowptrP, esrcP, n);

    scan_bins_kernel<<<1, 512, 0, stream>>>(binCntN, nbin, binBaseN, gCur);
    bin_scatter_kernel<<<(En + 4095) / 4096, 256, 0, stream>>>(ns, nd, En, binBaseN, gCur, binned, nbin);
    bin_finalize_kernel<<<nbin, 256, 0, stream>>>(binned, binBaseN, rowptrN, esrcN, n);

    // ---------------- Layer 1 ----------------
    scalars1_kernel<<<512, B, 0, stream>>>(x, a1b, a1u, S, XH, n);
    wgt1_kernel<<<nbin, 512, 0, stream>>>(esrcP, binBaseP, esrcN, binBaseN, S,
                                          WGT, WGT + Ep, RDEN, RDEN + n, n);
    agg64_kernel<<<aggBlocks, 256, 0, stream>>>(
        rowptrP, esrcP, WGT,      RDEN,
        rowptrN, esrcN, WGT + Ep, RDEN + n,
        XH, AGGH1, n);
    mlp1f_kernel<<<mlpBlocks, 256, 0, stream>>>(AGGH1, XH, WPK1, A2PK,
                                                b1b, b1u, ZH, S, n, ngrp);

    // ---------------- Layer 2 ----------------
    wgt2_kernel<<<nbin, 512, 0, stream>>>(esrcP, binBaseP, esrcN, binBaseN, S,
                                          (unsigned*)WGT, (unsigned*)WGT + Ep,
                                          RDEN, RDEN + n, RDEN + 2 * (size_t)n, RDEN + 3 * (size_t)n, n);
    agg32pair_kernel<<<aggBlocks, 256, 0, stream>>>(
        rowptrP, esrcP, (unsigned*)WGT,      RDEN,                 RDEN + n,
        rowptrN, esrcN, (unsigned*)WGT + Ep, RDEN + 2 * (size_t)n, RDEN + 3 * (size_t)n,
        ZH, AGGH, n);
    mlp2_kernel<<<mlpBlocks, 256, 0, stream>>>(AGGH, ZH, WPK2, b2b, b2u, out, n, ngrp);
}